// Round 3
// baseline (1204.245 us; speedup 1.0000x reference)
//
#include <hip/hip_runtime.h>
#include <hip/hip_fp16.h>

typedef _Float16 half_t;
typedef _Float16 half8 __attribute__((ext_vector_type(8)));
typedef float floatx4 __attribute__((ext_vector_type(4)));
typedef int   int4v  __attribute__((ext_vector_type(4)));

// ---- sizes ----
#define T_STEPS 300
#define NMB     1024                 // N*M batch
#define BS      16                   // steps per staged block
#define NBLK    19                   // ceil(300/16)

// ws layout (bytes)
#define XT_OFF   0ULL
#define XT_BYTES ((unsigned long long)(T_STEPS*NMB + 16)*64*2)
#define HS0_OFF  (XT_OFF + XT_BYTES)
#define HS0_BYTES ((unsigned long long)(T_STEPS*NMB + 16)*128*2)
#define WCH_OFF  (HS0_OFF + HS0_BYTES)        // wcomb as f16 [512][64]
#define WCH_BYTES (512ULL*64*2)
#define BC_OFF   (WCH_OFF + WCH_BYTES)        // biasc f32 [512]
#define BC_BYTES (512ULL*4)
#define FLAG_OFF (BC_OFF + BC_BYTES)          // 256 flags, 64B stride

// L_hat = -D^-1/2 A D^-1/2 for the hardcoded 15-node skeleton (row=dst, col=src)
#define S2 0.70710678118654752f
#define QH 0.5f
#define UU 0.40824829046386302f
#define TH 0.33333333333333333f
__constant__ float LHAT[225] = {
  0,0,-S2,0,0,0,0,0,0,0,0,0,0,0,0,
  0,0,0,-S2,0,0,0,0,0,0,0,0,0,0,0,
  -S2,0,0,0,-QH,0,0,0,0,0,0,0,0,0,0,
  0,-S2,0,0,0,-QH,0,0,0,0,0,0,0,0,0,
  0,0,-QH,0,0,0,0,0,0,0,0,0,0,0,-UU,
  0,0,0,-QH,0,0,0,0,0,0,0,0,0,0,-UU,
  0,0,0,0,0,0,0,0,-S2,0,0,0,0,0,0,
  0,0,0,0,0,0,0,0,0,-S2,0,0,0,0,0,
  0,0,0,0,0,0,-S2,0,0,0,-QH,0,0,0,0,
  0,0,0,0,0,0,0,-S2,0,0,0,-QH,0,0,0,
  0,0,0,0,0,0,0,0,-QH,0,0,0,0,-UU,0,
  0,0,0,0,0,0,0,0,0,-QH,0,0,0,-UU,0,
  0,0,0,0,0,0,0,0,0,0,0,0,0,0,0,
  0,0,0,0,0,0,0,0,0,0,-UU,-UU,0,0,0,
  0,0,0,0,-UU,-UU,0,0,0,0,0,0,0,-TH,0
};

// Fast gate math: v_exp_f32 + v_rcp_f32 (approx, ~1 ulp).
__device__ __forceinline__ float frcp(float x)  { return __builtin_amdgcn_rcpf(x); }
__device__ __forceinline__ float fsig(float x)  { return frcp(1.f + __expf(-x)); }
__device__ __forceinline__ float ftanh(float x) { return 2.f*frcp(1.f + __expf(-2.f*x)) - 1.f; }

__device__ __forceinline__ half8 load_w8(const float* p) {
  const float4* q = (const float4*)p;
  float4 a = q[0], b = q[1];
  half8 f;
  f[0]=(half_t)a.x; f[1]=(half_t)a.y; f[2]=(half_t)a.z; f[3]=(half_t)a.w;
  f[4]=(half_t)b.x; f[5]=(half_t)b.y; f[6]=(half_t)b.z; f[7]=(half_t)b.w;
  return f;
}

// Force true register residency of weight fragments (kills per-step remat).
__device__ __forceinline__ void pin(half8& f) {
  int4v t = __builtin_bit_cast(int4v, f);
  asm volatile("" : "+v"(t));
  f = __builtin_bit_cast(half8, t);
}
__device__ __forceinline__ void pinf(floatx4& f) {
  int4v t = __builtin_bit_cast(int4v, f);
  asm volatile("" : "+v"(t));
  f = __builtin_bit_cast(floatx4, t);
}

// Consumer-side block gate: relaxed poll (no cache maintenance per spin) + one acquire.
__device__ __forceinline__ void wait_flag(const int* f, int want, int tid) {
  if (tid == 0) {
    while (__hip_atomic_load(f, __ATOMIC_RELAXED, __HIP_MEMORY_SCOPE_AGENT) < want)
      __builtin_amdgcn_s_sleep(8);
    (void)__hip_atomic_load(f, __ATOMIC_ACQUIRE, __HIP_MEMORY_SCOPE_AGENT);
  }
  __syncthreads();
}

// ---- K0: fold ChebConv into layer-0 input projection: wcomb_h f16[512][64], biasc[512]
// Also zeroes the producer->consumer block flags (must happen every replay).
__global__ void k_prep(const float* __restrict__ w0, const float* __restrict__ w1,
                       const float* __restrict__ cb, const float* __restrict__ wih0,
                       const float* __restrict__ bih0, const float* __restrict__ bhh0,
                       half_t* __restrict__ wcomb_h, float* __restrict__ biasc,
                       int* __restrict__ flags) {
  const int n = threadIdx.x; // 512 threads, 1 block
  if (n < 256) flags[n*16] = 0;
  float wrow[45];
  #pragma unroll
  for (int i=0;i<45;i++) wrow[i] = wih0[n*45+i];
  float P[45];
  #pragma unroll
  for (int i=0;i<15;i++)
    #pragma unroll
    for (int c=0;c<3;c++) {
      float s = 0.f;
      #pragma unroll
      for (int cp=0;cp<3;cp++) s += wrow[i*3+cp]*w1[cp*3+c];
      P[i*3+c] = s;
    }
  #pragma unroll
  for (int j=0;j<15;j++)
    #pragma unroll
    for (int c=0;c<3;c++) {
      float s = 0.f;
      #pragma unroll
      for (int cp=0;cp<3;cp++) s += wrow[j*3+cp]*w0[cp*3+c];
      #pragma unroll
      for (int i=0;i<15;i++) s += LHAT[i*15+j]*P[i*3+c];
      wcomb_h[n*64 + j*3+c] = (half_t)s;
    }
  for (int k=45;k<64;k++) wcomb_h[n*64+k] = (half_t)0.f;
  float b = bih0[n] + bhh0[n];
  #pragma unroll
  for (int i=0;i<15;i++)
    #pragma unroll
    for (int cp=0;cp<3;cp++) b += wrow[i*3+cp]*cb[cp];
  biasc[n] = b;
}

// ---- K0b: x1 [N,C,T,V,M] fp32 -> xt [t*1024+nm][64] fp16 (features v*3+c, 45 valid)
__global__ void k_xpose(const float* __restrict__ x1, half_t* __restrict__ xt) {
  const int id = blockIdx.x*256 + threadIdx.x;   // exactly 512*3*300*15 = 6,912,000
  const int v  = id % 15;
  const int r1 = id / 15;
  const int t  = r1 % 300;
  const int r2 = r1 / 300;
  const int c  = r2 % 3;
  const int n  = r2 / 3;
  const float2 f = ((const float2*)x1)[id];      // m=0,1 pair, coalesced
  const size_t row = (size_t)t*NMB + n*2;
  xt[row*64     + v*3 + c] = (half_t)f.x;
  xt[(row+1)*64 + v*3 + c] = (half_t)f.y;
}

// ---- Fused LSTM: PLAIN launch (cooperative launch is rejected under hipGraph
// capture -> silently dropped dispatch; that was R2's failure). 512 WGs x 512
// threads, 2 WGs/CU (LDS 40.2KB x2 <= 160KB, VGPR <= 128 via launch_bounds(512,4),
// 16 waves <= 32) so all blocks are co-resident in practice. Liveness does NOT
// depend on co-residency: producers (blocks 0..255) never wait and are dispatched
// first (blockIdx order); consumers only spin on flags producers monotonically
// advance. Worst-case serialization is correct, just slow.
// WGs 0..255   = layer-0 producer: writes hs0 in 16-step blocks, publishes each
//               with an agent-scope release flag store (after __syncthreads drains
//               the stores).
// WGs 256..511 = layer-1 consumer + FC/softmax: relaxed-polls the paired flag, one
//               agent-acquire, then prefetches the hs0 block. Block i and i+256
//               land on the same XCD (256%8==0) so the handoff is L2-local.
__launch_bounds__(512, 4)
__global__ void k_lstm_fused(const half_t* __restrict__ xt, const half_t* __restrict__ wch,
                             const float* __restrict__ biasc, const float* __restrict__ whh0,
                             half_t* __restrict__ hs0,
                             const float* __restrict__ wih1, const float* __restrict__ whh1,
                             const float* __restrict__ bih1, const float* __restrict__ bhh1,
                             const float* __restrict__ fcw, const float* __restrict__ fcb,
                             float* __restrict__ out, int* __restrict__ flags) {
  __shared__ __align__(16) char smem[40192];
  const int tid = threadIdx.x;
  const int wave = tid>>6, lane = tid&63, quad = lane>>4, l16 = lane&15;

  if (blockIdx.x < 256) {
    // ================= layer-0 producer =================
    auto xs = (half_t (*)[BS][4][80])smem;          // [2][16][4][80], 20480 B
    auto hr = (half_t (*)[4][144])(smem + 20480);   // [16][4][144],  18432 B
    const int wg  = blockIdx.x;
    const int nm0 = wg*4;
    int* flag = flags + wg*16;

    for (int i=tid; i<4*144; i+=512) (&hr[15][0][0])[i] = (half_t)0.f;

    half8 whhF[4][4];
    half8 wcF [4][2];
    float bias[4];
    #pragma unroll
    for (int nt=0; nt<4; nt++) {
      const int gcol = nt*128 + wave*16 + l16;
      #pragma unroll
      for (int kc=0; kc<4; kc++) { whhF[nt][kc] = load_w8(whh0 + gcol*128 + kc*32 + quad*8); pin(whhF[nt][kc]); }
      #pragma unroll
      for (int kc=0; kc<2; kc++) { wcF[nt][kc] = *(const half8*)(wch + gcol*64 + kc*32 + quad*8); pin(wcF[nt][kc]); }
      bias[nt] = biasc[gcol];
    }
    float cst = 0.f;
    floatx4 z4 = {0.f,0.f,0.f,0.f}; pinf(z4);

    const int sS = tid>>5;          // step in block 0..15
    const int sR = (tid>>3)&3;      // batch row 0..3
    const int sC = (tid&7)*8;       // col 0..56

    float4 ld = *(const float4*)(xt + ((size_t)sS*NMB + nm0 + sR)*64 + sC);  // block 0
    *(half8*)&xs[0][sS][sR][sC] = __builtin_bit_cast(half8, ld);
    __syncthreads();

    for (int b=0; b<NBLK; b++) {
      const int bs = b*BS, buf = b&1;
      const int cnt = (T_STEPS - bs < BS) ? (T_STEPS - bs) : BS;
      const int ngr = cnt>>2;       // groups of 4 steps (cnt is 16 or 12)
      if (b+1 < NBLK) {             // prefetch next block into regs
        int tt = bs + BS + sS; if (tt > 299) tt = 299;
        ld = *(const float4*)(xt + ((size_t)tt*NMB + nm0 + sR)*64 + sC);
      }
      for (int g=0; g<ngr; g++) {
        const int s0 = g*4;
        // ---- batched xproj for steps s0..s0+3 (16 distinct A rows, batch-major)
        floatx4 xp[4];
        {
          const half_t* xrow = &xs[buf][s0 + (l16&3)][l16>>2][0];
          half8 xA[2];
          #pragma unroll
          for (int kc=0; kc<2; kc++) xA[kc] = *(const half8*)(xrow + kc*32 + quad*8);
          #pragma unroll
          for (int nt=0; nt<4; nt++) {
            floatx4 a = {bias[nt],bias[nt],bias[nt],bias[nt]};
            a = __builtin_amdgcn_mfma_f32_16x16x32_f16(xA[0], wcF[nt][0], a, 0,0,0);
            a = __builtin_amdgcn_mfma_f32_16x16x32_f16(xA[1], wcF[nt][1], a, 0,0,0);
            xp[nt] = a;
          }
        }
        #pragma unroll
        for (int j=0; j<4; j++) {
          const int t = bs + s0 + j;
          if (g == 0 && j == 1 && b+1 < NBLK)   // stage next block
            *(half8*)&xs[buf^1][sS][sR][sC] = __builtin_bit_cast(half8, ld);

          // recurrent h-chain, zero-C-init (bias+xproj added at extraction)
          half8 hA[4];
          const half_t* hrow = &hr[(t+15)&15][l16&3][0];
          #pragma unroll
          for (int kc=0; kc<4; kc++) hA[kc] = *(const half8*)(hrow + kc*32 + quad*8);
          floatx4 ah[4];
          #pragma unroll
          for (int nt=0; nt<4; nt++) {
            floatx4 a = z4;
            #pragma unroll
            for (int kc=0; kc<4; kc++)
              a = __builtin_amdgcn_mfma_f32_16x16x32_f16(hA[kc], whhF[nt][kc], a, 0,0,0);
            ah[nt] = a;
          }
          {
            const float gi = ah[0][quad] + xp[0][j];
            const float gf = ah[1][quad] + xp[1][j];
            const float gg = ah[2][quad] + xp[2][j];
            const float go = ah[3][quad] + xp[3][j];
            cst = fsig(gf)*cst + fsig(gi)*ftanh(gg);
            hr[t&15][quad][wave*16 + l16] = (half_t)(fsig(go)*ftanh(cst));
          }
          __syncthreads();
        }
      }
      // bulk store this block's h to hs0, then publish (release) to the paired consumer
      {
        const int hS = tid>>5, hR = (tid>>3)&3, hC = (tid&7)*16;
        if (hS < cnt) {
          half8 a0 = *(const half8*)&hr[(bs+hS)&15][hR][hC];
          half8 a1 = *(const half8*)&hr[(bs+hS)&15][hR][hC+8];
          half_t* dst = hs0 + ((size_t)(bs+hS)*NMB + nm0 + hR)*128 + hC;
          *(half8*)dst = a0; *(half8*)(dst+8) = a1;
        }
      }
      __syncthreads();   // all stores retired (vmcnt 0) before publish
      if (tid == 0)
        __hip_atomic_store(flag, b+1, __ATOMIC_RELEASE, __HIP_MEMORY_SCOPE_AGENT);
    }
  } else {
    // ================= layer-1 consumer + FC/softmax =================
    auto xs = (half_t (*)[BS][4][144])smem;          // [2][16][4][144], 36864 B
    auto h2 = (half_t (*)[4][144])(smem + 36864);    // [2][4][144],      2304 B
    float* logits_lds = (float*)(smem + 39168);      // 240 f32
    const int wg  = blockIdx.x - 256;
    const int nm0 = wg*4;
    const int* flag = flags + wg*16;

    for (int i=tid; i<2*4*144; i+=512) (&h2[0][0][0])[i] = (half_t)0.f;

    half8 wxF[4][4], whF[4][4];
    float bias[4];
    #pragma unroll
    for (int nt=0; nt<4; nt++) {
      const int gcol = nt*128 + wave*16 + l16;
      #pragma unroll
      for (int kc=0; kc<4; kc++) {
        wxF[nt][kc] = load_w8(wih1 + gcol*128 + kc*32 + quad*8); pin(wxF[nt][kc]);
        whF[nt][kc] = load_w8(whh1 + gcol*128 + kc*32 + quad*8); pin(whF[nt][kc]);
      }
      bias[nt] = bih1[gcol] + bhh1[gcol];
    }
    float cst = 0.f;
    floatx4 z4 = {0.f,0.f,0.f,0.f}; pinf(z4);

    const int sS = tid>>5;          // step 0..15
    const int sR = (tid>>3)&3;      // row 0..3
    const int sC = (tid&7)*16;      // col 0..112

    wait_flag(flag, 1, tid);        // hs0 block 0 ready
    float4 ld0, ld1;
    { const half_t* src = hs0 + ((size_t)sS*NMB + nm0 + sR)*128 + sC;
      ld0 = *(const float4*)src; ld1 = *(const float4*)(src+8); }
    *(half8*)&xs[0][sS][sR][sC]   = __builtin_bit_cast(half8, ld0);
    *(half8*)&xs[0][sS][sR][sC+8] = __builtin_bit_cast(half8, ld1);
    __syncthreads();

    for (int b=0; b<NBLK; b++) {
      const int bs = b*BS, buf = b&1;
      const int cnt = (T_STEPS - bs < BS) ? (T_STEPS - bs) : BS;
      const int ngr = cnt>>2;
      if (b+1 < NBLK) {
        wait_flag(flag, b+2, tid);  // hs0 block b+1 ready before prefetch
        int tt = bs + BS + sS; if (tt > 299) tt = 299;
        const half_t* src = hs0 + ((size_t)tt*NMB + nm0 + sR)*128 + sC;
        ld0 = *(const float4*)src; ld1 = *(const float4*)(src+8);
      }
      for (int g=0; g<ngr; g++) {
        const int s0 = g*4;
        // ---- batched xproj for steps s0..s0+3 (16 distinct A-rows, batch-major)
        floatx4 xp[4];
        {
          const half_t* xrow = &xs[buf][s0 + (l16&3)][l16>>2][0];
          half8 xA[4];
          #pragma unroll
          for (int kc=0; kc<4; kc++) xA[kc] = *(const half8*)(xrow + kc*32 + quad*8);
          #pragma unroll
          for (int nt=0; nt<4; nt++) {
            floatx4 a = {bias[nt],bias[nt],bias[nt],bias[nt]};
            #pragma unroll
            for (int kc=0; kc<4; kc++)
              a = __builtin_amdgcn_mfma_f32_16x16x32_f16(xA[kc], wxF[nt][kc], a, 0,0,0);
            xp[nt] = a;
          }
        }
        #pragma unroll
        for (int j=0; j<4; j++) {
          const int t = bs + s0 + j;
          if (g == 0 && j == 1 && b+1 < NBLK) {
            *(half8*)&xs[buf^1][sS][sR][sC]   = __builtin_bit_cast(half8, ld0);
            *(half8*)&xs[buf^1][sS][sR][sC+8] = __builtin_bit_cast(half8, ld1);
          }
          // recurrent h-chain, zero-C-init
          half8 hA[4];
          const half_t* hrow = &h2[t&1][l16&3][0];
          #pragma unroll
          for (int kc=0; kc<4; kc++) hA[kc] = *(const half8*)(hrow + kc*32 + quad*8);
          floatx4 ah[4];
          #pragma unroll
          for (int nt=0; nt<4; nt++) {
            floatx4 a = z4;
            #pragma unroll
            for (int kc=0; kc<4; kc++)
              a = __builtin_amdgcn_mfma_f32_16x16x32_f16(hA[kc], whF[nt][kc], a, 0,0,0);
            ah[nt] = a;
          }
          {
            const float gi = ah[0][quad] + xp[0][j];
            const float gf = ah[1][quad] + xp[1][j];
            const float gg = ah[2][quad] + xp[2][j];
            const float go = ah[3][quad] + xp[3][j];
            cst = fsig(gf)*cst + fsig(gi)*ftanh(gg);
            h2[(t+1)&1][quad][wave*16 + l16] = (half_t)(fsig(go)*ftanh(cst));
          }
          __syncthreads();
        }
      }
    }

    // ---- FC (60 classes) + softmax; h1[299] in h2[0] rows 0..3
    if (tid < 240) {
      const int r2 = tid/60, cls = tid%60;
      float s = fcb[cls];
      for (int k2=0; k2<128; k2++) s += (float)h2[0][r2][k2] * fcw[cls*128+k2];
      logits_lds[r2*60+cls] = s;
    }
    __syncthreads();
    if (tid < 4) {
      float m = -1e30f;
      for (int j=0; j<60; j++) m = fmaxf(m, logits_lds[tid*60+j]);
      float s = 0.f;
      for (int j=0; j<60; j++) s += __expf(logits_lds[tid*60+j]-m);
      const float inv = frcp(s);
      for (int j=0; j<60; j++) out[(nm0+tid)*60+j] = __expf(logits_lds[tid*60+j]-m)*inv;
    }
  }
}

extern "C" void kernel_launch(void* const* d_in, const int* in_sizes, int n_in,
                              void* d_out, int out_size, void* d_ws, size_t ws_size,
                              hipStream_t stream) {
  const float* x1      = (const float*)d_in[0];
  const float* cheb_w0 = (const float*)d_in[2];
  const float* cheb_w1 = (const float*)d_in[3];
  const float* cheb_b  = (const float*)d_in[4];
  const float* wih0    = (const float*)d_in[5];
  const float* whh0    = (const float*)d_in[6];
  const float* bih0    = (const float*)d_in[7];
  const float* bhh0    = (const float*)d_in[8];
  const float* wih1    = (const float*)d_in[9];
  const float* whh1    = (const float*)d_in[10];
  const float* bih1    = (const float*)d_in[11];
  const float* bhh1    = (const float*)d_in[12];
  const float* fc_w    = (const float*)d_in[13];
  const float* fc_b    = (const float*)d_in[14];

  char* ws = (char*)d_ws;
  half_t* xt    = (half_t*)(ws + XT_OFF);
  half_t* hs0   = (half_t*)(ws + HS0_OFF);
  half_t* wch   = (half_t*)(ws + WCH_OFF);
  float*  biasc = (float*)(ws + BC_OFF);
  int*    flags = (int*)(ws + FLAG_OFF);

  k_prep <<<dim3(1),     dim3(512), 0, stream>>>(cheb_w0, cheb_w1, cheb_b, wih0, bih0, bhh0, wch, biasc, flags);
  k_xpose<<<dim3(27000), dim3(256), 0, stream>>>(x1, xt);
  k_lstm_fused<<<dim3(512), dim3(512), 0, stream>>>(
      xt, wch, biasc, whh0, hs0, wih1, whh1, bih1, bhh1, fc_w, fc_b, (float*)d_out, flags);
}

// Round 4
// 584.298 us; speedup vs baseline: 2.0610x; 2.0610x over previous
//
#include <hip/hip_runtime.h>
#include <hip/hip_fp16.h>

typedef _Float16 half_t;
typedef _Float16 half8 __attribute__((ext_vector_type(8)));
typedef float floatx4 __attribute__((ext_vector_type(4)));
typedef int   int4v  __attribute__((ext_vector_type(4)));

// ---- sizes ----
#define T_STEPS 300
#define NMB     1024                 // N*M batch
#define BS      16                   // steps per staged block
#define NBLK    19                   // ceil(300/16)

// ws layout (bytes)
#define XT_OFF   0ULL
#define XT_BYTES ((unsigned long long)(T_STEPS*NMB + 16)*64*2)
#define HS0_OFF  (XT_OFF + XT_BYTES)
#define HS0_BYTES ((unsigned long long)(T_STEPS*NMB + 16)*128*2)
#define WCH_OFF  (HS0_OFF + HS0_BYTES)        // wcomb as f16 [512][64]
#define WCH_BYTES (512ULL*64*2)
#define BC_OFF   (WCH_OFF + WCH_BYTES)        // biasc f32 [512]
#define BC_BYTES (512ULL*4)
#define FLAG_OFF (BC_OFF + BC_BYTES)          // 256 flags, 64B stride

// L_hat = -D^-1/2 A D^-1/2 for the hardcoded 15-node skeleton (row=dst, col=src)
#define S2 0.70710678118654752f
#define QH 0.5f
#define UU 0.40824829046386302f
#define TH 0.33333333333333333f
__constant__ float LHAT[225] = {
  0,0,-S2,0,0,0,0,0,0,0,0,0,0,0,0,
  0,0,0,-S2,0,0,0,0,0,0,0,0,0,0,0,
  -S2,0,0,0,-QH,0,0,0,0,0,0,0,0,0,0,
  0,-S2,0,0,0,-QH,0,0,0,0,0,0,0,0,0,
  0,0,-QH,0,0,0,0,0,0,0,0,0,0,0,-UU,
  0,0,0,-QH,0,0,0,0,0,0,0,0,0,0,-UU,
  0,0,0,0,0,0,0,0,-S2,0,0,0,0,0,0,
  0,0,0,0,0,0,0,0,0,-S2,0,0,0,0,0,
  0,0,0,0,0,0,-S2,0,0,0,-QH,0,0,0,0,
  0,0,0,0,0,0,0,-S2,0,0,0,-QH,0,0,0,
  0,0,0,0,0,0,0,0,-QH,0,0,0,0,-UU,0,
  0,0,0,0,0,0,0,0,0,-QH,0,0,0,-UU,0,
  0,0,0,0,0,0,0,0,0,0,0,0,0,0,0,
  0,0,0,0,0,0,0,0,0,0,-UU,-UU,0,0,0,
  0,0,0,0,-UU,-UU,0,0,0,0,0,0,0,-TH,0
};

// Fast gate math: v_exp_f32 + v_rcp_f32 (approx, ~1 ulp).
__device__ __forceinline__ float frcp(float x)  { return __builtin_amdgcn_rcpf(x); }
__device__ __forceinline__ float fsig(float x)  { return frcp(1.f + __expf(-x)); }
__device__ __forceinline__ float ftanh(float x) { return 2.f*frcp(1.f + __expf(-2.f*x)) - 1.f; }

__device__ __forceinline__ half8 load_w8(const float* p) {
  const float4* q = (const float4*)p;
  float4 a = q[0], b = q[1];
  half8 f;
  f[0]=(half_t)a.x; f[1]=(half_t)a.y; f[2]=(half_t)a.z; f[3]=(half_t)a.w;
  f[4]=(half_t)b.x; f[5]=(half_t)b.y; f[6]=(half_t)b.z; f[7]=(half_t)b.w;
  return f;
}

// Force true register residency of weight fragments (kills per-step remat).
__device__ __forceinline__ void pin(half8& f) {
  int4v t = __builtin_bit_cast(int4v, f);
  asm volatile("" : "+v"(t));
  f = __builtin_bit_cast(half8, t);
}
__device__ __forceinline__ void pinf(floatx4& f) {
  int4v t = __builtin_bit_cast(int4v, f);
  asm volatile("" : "+v"(t));
  f = __builtin_bit_cast(floatx4, t);
}

// Consumer-side block gate: relaxed poll (no cache maintenance per spin) + one acquire.
__device__ __forceinline__ void wait_flag(const int* f, int want, int tid) {
  if (tid == 0) {
    while (__hip_atomic_load(f, __ATOMIC_RELAXED, __HIP_MEMORY_SCOPE_AGENT) < want)
      __builtin_amdgcn_s_sleep(8);
    (void)__hip_atomic_load(f, __ATOMIC_ACQUIRE, __HIP_MEMORY_SCOPE_AGENT);
  }
  __syncthreads();
}

// ---- K0: fold ChebConv into layer-0 input projection: wcomb_h f16[512][64], biasc[512]
// Also zeroes the producer->consumer block flags (must happen every replay).
__global__ void k_prep(const float* __restrict__ w0, const float* __restrict__ w1,
                       const float* __restrict__ cb, const float* __restrict__ wih0,
                       const float* __restrict__ bih0, const float* __restrict__ bhh0,
                       half_t* __restrict__ wcomb_h, float* __restrict__ biasc,
                       int* __restrict__ flags) {
  const int n = threadIdx.x; // 512 threads, 1 block
  if (n < 256) flags[n*16] = 0;
  float wrow[45];
  #pragma unroll
  for (int i=0;i<45;i++) wrow[i] = wih0[n*45+i];
  float P[45];
  #pragma unroll
  for (int i=0;i<15;i++)
    #pragma unroll
    for (int c=0;c<3;c++) {
      float s = 0.f;
      #pragma unroll
      for (int cp=0;cp<3;cp++) s += wrow[i*3+cp]*w1[cp*3+c];
      P[i*3+c] = s;
    }
  #pragma unroll
  for (int j=0;j<15;j++)
    #pragma unroll
    for (int c=0;c<3;c++) {
      float s = 0.f;
      #pragma unroll
      for (int cp=0;cp<3;cp++) s += wrow[j*3+cp]*w0[cp*3+c];
      #pragma unroll
      for (int i=0;i<15;i++) s += LHAT[i*15+j]*P[i*3+c];
      wcomb_h[n*64 + j*3+c] = (half_t)s;
    }
  for (int k=45;k<64;k++) wcomb_h[n*64+k] = (half_t)0.f;
  float b = bih0[n] + bhh0[n];
  #pragma unroll
  for (int i=0;i<15;i++)
    #pragma unroll
    for (int cp=0;cp<3;cp++) b += wrow[i*3+cp]*cb[cp];
  biasc[n] = b;
}

// ---- K0b: x1 [N,C,T,V,M] fp32 -> xt [t*1024+nm][64] fp16 (features v*3+c, 45 valid)
__global__ void k_xpose(const float* __restrict__ x1, half_t* __restrict__ xt) {
  const int id = blockIdx.x*256 + threadIdx.x;   // exactly 512*3*300*15 = 6,912,000
  const int v  = id % 15;
  const int r1 = id / 15;
  const int t  = r1 % 300;
  const int r2 = r1 / 300;
  const int c  = r2 % 3;
  const int n  = r2 / 3;
  const float2 f = ((const float2*)x1)[id];      // m=0,1 pair, coalesced
  const size_t row = (size_t)t*NMB + n*2;
  xt[row*64     + v*3 + c] = (half_t)f.x;
  xt[(row+1)*64 + v*3 + c] = (half_t)f.y;
}

// ---- Fused LSTM, plain (graph-capturable) launch. 512 WGs x 512 threads.
// LAUNCH_BOUNDS NOTE (R3 post-mortem): (512,4) capped VGPRs at 64 -> weight frags
// spilled to scratch -> 2.1GB of scratch fetch, 1082us. Empirical mapping on this
// toolchain: (512,2) -> cap 128 (split kernels compiled at 112-116, no spill).
// 2 WGs/CU co-residency needs only VGPR<=128 + LDS 40.4KBx2 <= 160KB, so (512,2)
// is the correct knob.
// WGs 0..255   = layer-0 producer: writes hs0 in 16-step blocks, publishes each
//               with an agent-scope release flag store (after __syncthreads drains
//               the stores).
// WGs 256..511 = layer-1 consumer + FC/softmax: relaxed-polls the paired flag, one
//               agent-acquire, then prefetches the hs0 block. Block i and i+256
//               land on the same XCD (256%8==0) so the handoff is L2-local.
// Liveness does NOT depend on co-residency: producers never wait and are dispatched
// first (blockIdx order); consumers only spin on flags producers monotonically
// advance. Worst-case serialization is correct, just slow.
__launch_bounds__(512, 2)
__global__ void k_lstm_fused(const half_t* __restrict__ xt, const half_t* __restrict__ wch,
                             const float* __restrict__ biasc, const float* __restrict__ whh0,
                             half_t* __restrict__ hs0,
                             const float* __restrict__ wih1, const float* __restrict__ whh1,
                             const float* __restrict__ bih1, const float* __restrict__ bhh1,
                             const float* __restrict__ fcw, const float* __restrict__ fcb,
                             float* __restrict__ out, int* __restrict__ flags) {
  __shared__ __align__(16) char smem[40192];
  const int tid = threadIdx.x;
  const int wave = tid>>6, lane = tid&63, quad = lane>>4, l16 = lane&15;

  if (blockIdx.x < 256) {
    // ================= layer-0 producer =================
    auto xs = (half_t (*)[BS][4][80])smem;          // [2][16][4][80], 20480 B
    auto hr = (half_t (*)[4][144])(smem + 20480);   // [16][4][144],  18432 B
    const int wg  = blockIdx.x;
    const int nm0 = wg*4;
    int* flag = flags + wg*16;

    for (int i=tid; i<4*144; i+=512) (&hr[15][0][0])[i] = (half_t)0.f;

    half8 whhF[4][4];
    half8 wcF [4][2];
    float bias[4];
    #pragma unroll
    for (int nt=0; nt<4; nt++) {
      const int gcol = nt*128 + wave*16 + l16;
      #pragma unroll
      for (int kc=0; kc<4; kc++) { whhF[nt][kc] = load_w8(whh0 + gcol*128 + kc*32 + quad*8); pin(whhF[nt][kc]); }
      #pragma unroll
      for (int kc=0; kc<2; kc++) { wcF[nt][kc] = *(const half8*)(wch + gcol*64 + kc*32 + quad*8); pin(wcF[nt][kc]); }
      bias[nt] = biasc[gcol];
    }
    float cst = 0.f;
    floatx4 z4 = {0.f,0.f,0.f,0.f}; pinf(z4);

    const int sS = tid>>5;          // step in block 0..15
    const int sR = (tid>>3)&3;      // batch row 0..3
    const int sC = (tid&7)*8;       // col 0..56

    float4 ld = *(const float4*)(xt + ((size_t)sS*NMB + nm0 + sR)*64 + sC);  // block 0
    *(half8*)&xs[0][sS][sR][sC] = __builtin_bit_cast(half8, ld);
    __syncthreads();

    for (int b=0; b<NBLK; b++) {
      const int bs = b*BS, buf = b&1;
      const int cnt = (T_STEPS - bs < BS) ? (T_STEPS - bs) : BS;
      const int ngr = cnt>>2;       // groups of 4 steps (cnt is 16 or 12)
      if (b+1 < NBLK) {             // prefetch next block into regs
        int tt = bs + BS + sS; if (tt > 299) tt = 299;
        ld = *(const float4*)(xt + ((size_t)tt*NMB + nm0 + sR)*64 + sC);
      }
      for (int g=0; g<ngr; g++) {
        const int s0 = g*4;
        // ---- batched xproj for steps s0..s0+3 (16 distinct A rows, batch-major)
        floatx4 xp[4];
        {
          const half_t* xrow = &xs[buf][s0 + (l16&3)][l16>>2][0];
          half8 xA[2];
          #pragma unroll
          for (int kc=0; kc<2; kc++) xA[kc] = *(const half8*)(xrow + kc*32 + quad*8);
          #pragma unroll
          for (int nt=0; nt<4; nt++) {
            floatx4 a = {bias[nt],bias[nt],bias[nt],bias[nt]};
            a = __builtin_amdgcn_mfma_f32_16x16x32_f16(xA[0], wcF[nt][0], a, 0,0,0);
            a = __builtin_amdgcn_mfma_f32_16x16x32_f16(xA[1], wcF[nt][1], a, 0,0,0);
            xp[nt] = a;
          }
        }
        #pragma unroll
        for (int j=0; j<4; j++) {
          const int t = bs + s0 + j;
          if (g == 0 && j == 1 && b+1 < NBLK)   // stage next block
            *(half8*)&xs[buf^1][sS][sR][sC] = __builtin_bit_cast(half8, ld);

          // recurrent h-chain, zero-C-init (bias+xproj added at extraction)
          half8 hA[4];
          const half_t* hrow = &hr[(t+15)&15][l16&3][0];
          #pragma unroll
          for (int kc=0; kc<4; kc++) hA[kc] = *(const half8*)(hrow + kc*32 + quad*8);
          floatx4 ah[4];
          #pragma unroll
          for (int nt=0; nt<4; nt++) {
            floatx4 a = z4;
            #pragma unroll
            for (int kc=0; kc<4; kc++)
              a = __builtin_amdgcn_mfma_f32_16x16x32_f16(hA[kc], whhF[nt][kc], a, 0,0,0);
            ah[nt] = a;
          }
          {
            const float gi = ah[0][quad] + xp[0][j];
            const float gf = ah[1][quad] + xp[1][j];
            const float gg = ah[2][quad] + xp[2][j];
            const float go = ah[3][quad] + xp[3][j];
            cst = fsig(gf)*cst + fsig(gi)*ftanh(gg);
            hr[t&15][quad][wave*16 + l16] = (half_t)(fsig(go)*ftanh(cst));
          }
          __syncthreads();
        }
      }
      // bulk store this block's h to hs0, then publish (release) to the paired consumer
      {
        const int hS = tid>>5, hR = (tid>>3)&3, hC = (tid&7)*16;
        if (hS < cnt) {
          half8 a0 = *(const half8*)&hr[(bs+hS)&15][hR][hC];
          half8 a1 = *(const half8*)&hr[(bs+hS)&15][hR][hC+8];
          half_t* dst = hs0 + ((size_t)(bs+hS)*NMB + nm0 + hR)*128 + hC;
          *(half8*)dst = a0; *(half8*)(dst+8) = a1;
        }
      }
      __syncthreads();   // all stores retired (vmcnt 0) before publish
      if (tid == 0)
        __hip_atomic_store(flag, b+1, __ATOMIC_RELEASE, __HIP_MEMORY_SCOPE_AGENT);
    }
  } else {
    // ================= layer-1 consumer + FC/softmax =================
    auto xs = (half_t (*)[BS][4][144])smem;          // [2][16][4][144], 36864 B
    auto h2 = (half_t (*)[4][144])(smem + 36864);    // [2][4][144],      2304 B
    float* logits_lds = (float*)(smem + 39168);      // 240 f32
    const int wg  = blockIdx.x - 256;
    const int nm0 = wg*4;
    const int* flag = flags + wg*16;

    for (int i=tid; i<2*4*144; i+=512) (&h2[0][0][0])[i] = (half_t)0.f;

    half8 wxF[4][4], whF[4][4];
    float bias[4];
    #pragma unroll
    for (int nt=0; nt<4; nt++) {
      const int gcol = nt*128 + wave*16 + l16;
      #pragma unroll
      for (int kc=0; kc<4; kc++) {
        wxF[nt][kc] = load_w8(wih1 + gcol*128 + kc*32 + quad*8); pin(wxF[nt][kc]);
        whF[nt][kc] = load_w8(whh1 + gcol*128 + kc*32 + quad*8); pin(whF[nt][kc]);
      }
      bias[nt] = bih1[gcol] + bhh1[gcol];
    }
    float cst = 0.f;
    floatx4 z4 = {0.f,0.f,0.f,0.f}; pinf(z4);

    const int sS = tid>>5;          // step 0..15
    const int sR = (tid>>3)&3;      // row 0..3
    const int sC = (tid&7)*16;      // col 0..112

    wait_flag(flag, 1, tid);        // hs0 block 0 ready
    float4 ld0, ld1;
    { const half_t* src = hs0 + ((size_t)sS*NMB + nm0 + sR)*128 + sC;
      ld0 = *(const float4*)src; ld1 = *(const float4*)(src+8); }
    *(half8*)&xs[0][sS][sR][sC]   = __builtin_bit_cast(half8, ld0);
    *(half8*)&xs[0][sS][sR][sC+8] = __builtin_bit_cast(half8, ld1);
    __syncthreads();

    for (int b=0; b<NBLK; b++) {
      const int bs = b*BS, buf = b&1;
      const int cnt = (T_STEPS - bs < BS) ? (T_STEPS - bs) : BS;
      const int ngr = cnt>>2;
      if (b+1 < NBLK) {
        wait_flag(flag, b+2, tid);  // hs0 block b+1 ready before prefetch
        int tt = bs + BS + sS; if (tt > 299) tt = 299;
        const half_t* src = hs0 + ((size_t)tt*NMB + nm0 + sR)*128 + sC;
        ld0 = *(const float4*)src; ld1 = *(const float4*)(src+8);
      }
      for (int g=0; g<ngr; g++) {
        const int s0 = g*4;
        // ---- batched xproj for steps s0..s0+3 (16 distinct A-rows, batch-major)
        floatx4 xp[4];
        {
          const half_t* xrow = &xs[buf][s0 + (l16&3)][l16>>2][0];
          half8 xA[4];
          #pragma unroll
          for (int kc=0; kc<4; kc++) xA[kc] = *(const half8*)(xrow + kc*32 + quad*8);
          #pragma unroll
          for (int nt=0; nt<4; nt++) {
            floatx4 a = {bias[nt],bias[nt],bias[nt],bias[nt]};
            #pragma unroll
            for (int kc=0; kc<4; kc++)
              a = __builtin_amdgcn_mfma_f32_16x16x32_f16(xA[kc], wxF[nt][kc], a, 0,0,0);
            xp[nt] = a;
          }
        }
        #pragma unroll
        for (int j=0; j<4; j++) {
          const int t = bs + s0 + j;
          if (g == 0 && j == 1 && b+1 < NBLK) {
            *(half8*)&xs[buf^1][sS][sR][sC]   = __builtin_bit_cast(half8, ld0);
            *(half8*)&xs[buf^1][sS][sR][sC+8] = __builtin_bit_cast(half8, ld1);
          }
          // recurrent h-chain, zero-C-init
          half8 hA[4];
          const half_t* hrow = &h2[t&1][l16&3][0];
          #pragma unroll
          for (int kc=0; kc<4; kc++) hA[kc] = *(const half8*)(hrow + kc*32 + quad*8);
          floatx4 ah[4];
          #pragma unroll
          for (int nt=0; nt<4; nt++) {
            floatx4 a = z4;
            #pragma unroll
            for (int kc=0; kc<4; kc++)
              a = __builtin_amdgcn_mfma_f32_16x16x32_f16(hA[kc], whF[nt][kc], a, 0,0,0);
            ah[nt] = a;
          }
          {
            const float gi = ah[0][quad] + xp[0][j];
            const float gf = ah[1][quad] + xp[1][j];
            const float gg = ah[2][quad] + xp[2][j];
            const float go = ah[3][quad] + xp[3][j];
            cst = fsig(gf)*cst + fsig(gi)*ftanh(gg);
            h2[(t+1)&1][quad][wave*16 + l16] = (half_t)(fsig(go)*ftanh(cst));
          }
          __syncthreads();
        }
      }
    }

    // ---- FC (60 classes) + softmax; h1[299] in h2[0] rows 0..3
    if (tid < 240) {
      const int r2 = tid/60, cls = tid%60;
      float s = fcb[cls];
      for (int k2=0; k2<128; k2++) s += (float)h2[0][r2][k2] * fcw[cls*128+k2];
      logits_lds[r2*60+cls] = s;
    }
    __syncthreads();
    if (tid < 4) {
      float m = -1e30f;
      for (int j=0; j<60; j++) m = fmaxf(m, logits_lds[tid*60+j]);
      float s = 0.f;
      for (int j=0; j<60; j++) s += __expf(logits_lds[tid*60+j]-m);
      const float inv = frcp(s);
      for (int j=0; j<60; j++) out[(nm0+tid)*60+j] = __expf(logits_lds[tid*60+j]-m)*inv;
    }
  }
}

extern "C" void kernel_launch(void* const* d_in, const int* in_sizes, int n_in,
                              void* d_out, int out_size, void* d_ws, size_t ws_size,
                              hipStream_t stream) {
  const float* x1      = (const float*)d_in[0];
  const float* cheb_w0 = (const float*)d_in[2];
  const float* cheb_w1 = (const float*)d_in[3];
  const float* cheb_b  = (const float*)d_in[4];
  const float* wih0    = (const float*)d_in[5];
  const float* whh0    = (const float*)d_in[6];
  const float* bih0    = (const float*)d_in[7];
  const float* bhh0    = (const float*)d_in[8];
  const float* wih1    = (const float*)d_in[9];
  const float* whh1    = (const float*)d_in[10];
  const float* bih1    = (const float*)d_in[11];
  const float* bhh1    = (const float*)d_in[12];
  const float* fc_w    = (const float*)d_in[13];
  const float* fc_b    = (const float*)d_in[14];

  char* ws = (char*)d_ws;
  half_t* xt    = (half_t*)(ws + XT_OFF);
  half_t* hs0   = (half_t*)(ws + HS0_OFF);
  half_t* wch   = (half_t*)(ws + WCH_OFF);
  float*  biasc = (float*)(ws + BC_OFF);
  int*    flags = (int*)(ws + FLAG_OFF);

  k_prep <<<dim3(1),     dim3(512), 0, stream>>>(cheb_w0, cheb_w1, cheb_b, wih0, bih0, bhh0, wch, biasc, flags);
  k_xpose<<<dim3(27000), dim3(256), 0, stream>>>(x1, xt);
  k_lstm_fused<<<dim3(512), dim3(512), 0, stream>>>(
      xt, wch, biasc, whh0, hs0, wih1, whh1, bih1, bhh1, fc_w, fc_b, (float*)d_out, flags);
}

// Round 5
// 458.282 us; speedup vs baseline: 2.6277x; 1.2750x over previous
//
#include <hip/hip_runtime.h>
#include <hip/hip_fp16.h>

typedef _Float16 half_t;
typedef _Float16 half8 __attribute__((ext_vector_type(8)));
typedef float floatx4 __attribute__((ext_vector_type(4)));
typedef int   int4v  __attribute__((ext_vector_type(4)));

// ---- sizes ----
#define T_STEPS 300
#define NMB     1024                 // N*M batch
#define BS      16                   // steps per staged block
#define NBLK    19                   // ceil(300/16)

// ws layout (bytes) -- xt region retained (unused) to keep offsets stable
#define XT_OFF   0ULL
#define XT_BYTES ((unsigned long long)(T_STEPS*NMB + 16)*64*2)
#define HS0_OFF  (XT_OFF + XT_BYTES)
#define HS0_BYTES ((unsigned long long)(T_STEPS*NMB + 16)*128*2)
#define WCH_OFF  (HS0_OFF + HS0_BYTES)        // wcomb as f16 [512][64]
#define WCH_BYTES (512ULL*64*2)
#define BC_OFF   (WCH_OFF + WCH_BYTES)        // biasc f32 [512]
#define BC_BYTES (512ULL*4)
#define FLAG_OFF (BC_OFF + BC_BYTES)          // flags, 64B stride

// L_hat = -D^-1/2 A D^-1/2 for the hardcoded 15-node skeleton (row=dst, col=src)
#define S2 0.70710678118654752f
#define QH 0.5f
#define UU 0.40824829046386302f
#define TH 0.33333333333333333f
__constant__ float LHAT[225] = {
  0,0,-S2,0,0,0,0,0,0,0,0,0,0,0,0,
  0,0,0,-S2,0,0,0,0,0,0,0,0,0,0,0,
  -S2,0,0,0,-QH,0,0,0,0,0,0,0,0,0,0,
  0,-S2,0,0,0,-QH,0,0,0,0,0,0,0,0,0,
  0,0,-QH,0,0,0,0,0,0,0,0,0,0,0,-UU,
  0,0,0,-QH,0,0,0,0,0,0,0,0,0,0,-UU,
  0,0,0,0,0,0,0,0,-S2,0,0,0,0,0,0,
  0,0,0,0,0,0,0,0,0,-S2,0,0,0,0,0,
  0,0,0,0,0,0,-S2,0,0,0,-QH,0,0,0,0,
  0,0,0,0,0,0,0,-S2,0,0,0,-QH,0,0,0,
  0,0,0,0,0,0,0,0,-QH,0,0,0,0,-UU,0,
  0,0,0,0,0,0,0,0,0,-QH,0,0,0,-UU,0,
  0,0,0,0,0,0,0,0,0,0,0,0,0,0,0,
  0,0,0,0,0,0,0,0,0,0,-UU,-UU,0,0,0,
  0,0,0,0,-UU,-UU,0,0,0,0,0,0,0,-TH,0
};

// Fast gate math: v_exp_f32 + v_rcp_f32 (approx, ~1 ulp).
__device__ __forceinline__ float frcp(float x)  { return __builtin_amdgcn_rcpf(x); }
__device__ __forceinline__ float fsig(float x)  { return frcp(1.f + __expf(-x)); }
__device__ __forceinline__ float ftanh(float x) { return 2.f*frcp(1.f + __expf(-2.f*x)) - 1.f; }

__device__ __forceinline__ half8 load_w8(const float* p) {
  const float4* q = (const float4*)p;
  float4 a = q[0], b = q[1];
  half8 f;
  f[0]=(half_t)a.x; f[1]=(half_t)a.y; f[2]=(half_t)a.z; f[3]=(half_t)a.w;
  f[4]=(half_t)b.x; f[5]=(half_t)b.y; f[6]=(half_t)b.z; f[7]=(half_t)b.w;
  return f;
}

// Force true register residency of weight fragments (kills per-step remat).
__device__ __forceinline__ void pin(half8& f) {
  int4v t = __builtin_bit_cast(int4v, f);
  asm volatile("" : "+v"(t));
  f = __builtin_bit_cast(half8, t);
}
__device__ __forceinline__ void pinf(floatx4& f) {
  int4v t = __builtin_bit_cast(int4v, f);
  asm volatile("" : "+v"(t));
  f = __builtin_bit_cast(floatx4, t);
}

// Consumer-side block gate: relaxed poll + one acquire.
__device__ __forceinline__ void wait_flag(const int* f, int want, int tid) {
  if (tid == 0) {
    while (__hip_atomic_load(f, __ATOMIC_RELAXED, __HIP_MEMORY_SCOPE_AGENT) < want)
      __builtin_amdgcn_s_sleep(8);
    (void)__hip_atomic_load(f, __ATOMIC_ACQUIRE, __HIP_MEMORY_SCOPE_AGENT);
  }
  __syncthreads();
}

// ---- K0: fold ChebConv into layer-0 input projection: wcomb_h f16[512][64], biasc[512]
// Also zeroes the producer->consumer block flags (must happen every replay).
__global__ void k_prep(const float* __restrict__ w0, const float* __restrict__ w1,
                       const float* __restrict__ cb, const float* __restrict__ wih0,
                       const float* __restrict__ bih0, const float* __restrict__ bhh0,
                       half_t* __restrict__ wcomb_h, float* __restrict__ biasc,
                       int* __restrict__ flags) {
  const int n = threadIdx.x; // 512 threads, 1 block
  if (n < 256) flags[n*16] = 0;
  float wrow[45];
  #pragma unroll
  for (int i=0;i<45;i++) wrow[i] = wih0[n*45+i];
  float P[45];
  #pragma unroll
  for (int i=0;i<15;i++)
    #pragma unroll
    for (int c=0;c<3;c++) {
      float s = 0.f;
      #pragma unroll
      for (int cp=0;cp<3;cp++) s += wrow[i*3+cp]*w1[cp*3+c];
      P[i*3+c] = s;
    }
  #pragma unroll
  for (int j=0;j<15;j++)
    #pragma unroll
    for (int c=0;c<3;c++) {
      float s = 0.f;
      #pragma unroll
      for (int cp=0;cp<3;cp++) s += wrow[j*3+cp]*w0[cp*3+c];
      #pragma unroll
      for (int i=0;i<15;i++) s += LHAT[i*15+j]*P[i*3+c];
      wcomb_h[n*64 + j*3+c] = (half_t)s;
    }
  for (int k=45;k<64;k++) wcomb_h[n*64+k] = (half_t)0.f;
  float b = bih0[n] + bhh0[n];
  #pragma unroll
  for (int i=0;i<15;i++)
    #pragma unroll
    for (int cp=0;cp<3;cp++) b += wrow[i*3+cp]*cb[cp];
  biasc[n] = b;
}

// ---- Fused LSTM on DISJOINT CUs. Grid 256 x 512 threads, ~80KB LDS/WG => exactly
// 1 WG/CU; blocks 0..127 = layer-0 producers, 128..255 = layer-1 consumers; the two
// layers overlap in time on different CUs (R4 post-mortem: same-CU 2-WG packing is
// impossible because unified VGPR+AGPR demand > 128/thread; rocprof VGPR_Count=116
// was arch-VGPRs only).
// M=8: each WG owns 8 batch rows; MFMA A carries 8 distinct rows (x2 replicated to
// 16), so per-row h-chain MFMA cost halves vs M=4 and one layer needs only 128 WGs.
// Lane ownership (derived from C layout row=quad*4+reg, col=l16, A row m -> h[m&7]):
//   lane (quad,l16) owns batches b(r2)=((quad&1)<<2)|(quad&2)|r2, r2=0,1 at
//   ah reg index (quad<2 ? r2 : r2+2).
// xproj batches 2 steps (A row = js*8+batch, step-major):
//   own-step values sit in regs r2 (quads 0-1: js=0) / r2+2 (quads 2-3: js=1);
//   the cross-step values come from lane^32 via __shfl_xor: xq0 (partner regs r2,
//   used by quads 0-1 at js=1), xq2 (partner regs r2+2, used by quads 2-3 at js=0).
// The producer also absorbs the old k_xpose: it reads x1 (f32) directly per
// 16-step block, converting to f16 into LDS (kills one launch + xt round trip).
__launch_bounds__(512, 1)
__global__ void k_lstm_fused(const float* __restrict__ x1, const half_t* __restrict__ wch,
                             const float* __restrict__ biasc, const float* __restrict__ whh0,
                             half_t* __restrict__ hs0,
                             const float* __restrict__ wih1, const float* __restrict__ whh1,
                             const float* __restrict__ bih1, const float* __restrict__ bhh1,
                             const float* __restrict__ fcw, const float* __restrict__ fcb,
                             float* __restrict__ out, int* __restrict__ flags) {
  __shared__ __align__(16) char smem[80384];
  const int tid = threadIdx.x;
  const int wave = tid>>6, lane = tid&63, quad = lane>>4, l16 = lane&15;
  const bool qlo = quad < 2;
  const int brow = ((quad&1)<<2) | (quad&2);   // first owned batch row
  const int colw = wave*16 + l16;              // owned h column

  if (blockIdx.x < 128) {
    // ================= layer-0 producer (8 rows, inline x-transpose) =============
    auto xs = (half_t (*)[BS][8][80])smem;            // [2][16][8][80] = 40960 B
    auto hr = (half_t (*)[8][144])(smem + 40960);     // [16][8][144]  = 36864 B
    const int wg  = blockIdx.x;
    const int nm0 = wg*8;
    const int n0t3 = wg*4*3;                          // (n0)*3 for x1 addressing
    int* flag = flags + wg*16;

    // zero xs once (cols 45..63 are never written; must be 0*-safe for MFMA A)
    for (int i=tid; i<2*BS*8*80; i+=512) ((half_t*)smem)[i] = (half_t)0.f;
    for (int i=tid; i<8*144; i+=512) (&hr[15][0][0])[i] = (half_t)0.f;

    half8 whhF[4][4]; half8 wcF[4][2]; float bias[4];
    #pragma unroll
    for (int nt=0; nt<4; nt++) {
      const int gcol = nt*128 + colw;
      #pragma unroll
      for (int kc=0; kc<4; kc++) { whhF[nt][kc] = load_w8(whh0 + gcol*128 + kc*32 + quad*8); pin(whhF[nt][kc]); }
      #pragma unroll
      for (int kc=0; kc<2; kc++) { wcF[nt][kc] = *(const half8*)(wch + gcol*64 + kc*32 + quad*8); pin(wcF[nt][kc]); }
      bias[nt] = biasc[gcol];
    }
    float cst0 = 0.f, cst1 = 0.f;
    floatx4 z4 = {0.f,0.f,0.f,0.f}; pinf(z4);

    // x staging: per block 4n x 3c x 16s x 15v = 2880 float2 (m-pair) items.
    // idx = ((nh*3 + c)*16 + sh)*15 + v  (v fastest -> 120B-contiguous strips)
    float2 xld[6];
    #define XDEC(IDX) const int v_=(IDX)%15; const int rA_=(IDX)/15; \
                      const int sh_=rA_&15; const int rB_=rA_>>4;    \
                      const int c_=rB_%3; const int nh_=rB_/3;
    #define XLOAD(TBASE) { _Pragma("unroll") for (int k=0;k<6;k++) { \
        const int idx=k*512+tid; if (idx<2880) { XDEC(idx)           \
          int tt=(TBASE)+sh_; if (tt>299) tt=299;                     \
          xld[k]=((const float2*)x1)[(size_t)((n0t3+nh_*3+c_)*300+tt)*15+v_]; } } }
    #define XWRITE(BUFI) { _Pragma("unroll") for (int k=0;k<6;k++) { \
        const int idx=k*512+tid; if (idx<2880) { XDEC(idx)           \
          xs[BUFI][sh_][nh_*2  ][v_*3+c_]=(half_t)xld[k].x;          \
          xs[BUFI][sh_][nh_*2+1][v_*3+c_]=(half_t)xld[k].y; } } }

    XLOAD(0); __syncthreads(); XWRITE(0);   // sync: zero-fill of xs must precede
    __syncthreads();

    for (int b=0; b<NBLK; b++) {
      const int bs = b*BS, buf = b&1;
      const int cnt = (T_STEPS - bs < BS) ? (T_STEPS - bs) : BS;
      const int ngr = cnt>>1;                 // 2-step groups
      if (b+1 < NBLK) XLOAD(bs + BS);
      for (int g=0; g<ngr; g++) {
        const int s0 = g*2;
        // ---- batched xproj (A row = js*8 + batch), bias in C-init
        floatx4 xp[4];
        {
          const half_t* xrow = &xs[buf][s0 + (l16>>3)][l16&7][0];
          #pragma unroll
          for (int nt=0; nt<4; nt++) xp[nt] = (floatx4){bias[nt],bias[nt],bias[nt],bias[nt]};
          #pragma unroll
          for (int kc=0; kc<2; kc++) {
            const half8 xa = *(const half8*)(xrow + kc*32 + quad*8);
            #pragma unroll
            for (int nt=0; nt<4; nt++)
              xp[nt] = __builtin_amdgcn_mfma_f32_16x16x32_f16(xa, wcF[nt][kc], xp[nt], 0,0,0);
          }
        }
        float xq0[4][2], xq2[4][2];
        #pragma unroll
        for (int nt=0; nt<4; nt++)
          #pragma unroll
          for (int r2=0; r2<2; r2++) {
            xq0[nt][r2] = __shfl_xor(xp[nt][r2],   32);
            xq2[nt][r2] = __shfl_xor(xp[nt][r2+2], 32);
          }
        #pragma unroll
        for (int js=0; js<2; js++) {
          const int t = bs + s0 + js;
          if (js==1 && g==0 && b+1 < NBLK) XWRITE(buf^1);
          // recurrent h-chain, zero-C-init
          floatx4 ah[4];
          #pragma unroll
          for (int nt=0; nt<4; nt++) ah[nt] = z4;
          {
            const half_t* hrow = &hr[(t+15)&15][l16&7][0];
            #pragma unroll
            for (int kc=0; kc<4; kc++) {
              const half8 ha = *(const half8*)(hrow + kc*32 + quad*8);
              #pragma unroll
              for (int nt=0; nt<4; nt++)
                ah[nt] = __builtin_amdgcn_mfma_f32_16x16x32_f16(ha, whhF[nt][kc], ah[nt], 0,0,0);
            }
          }
          #pragma unroll
          for (int r2=0; r2<2; r2++) {
            const float a0 = qlo ? ah[0][r2] : ah[0][r2+2];
            const float a1 = qlo ? ah[1][r2] : ah[1][r2+2];
            const float a2 = qlo ? ah[2][r2] : ah[2][r2+2];
            const float a3 = qlo ? ah[3][r2] : ah[3][r2+2];
            const float x0 = js==0 ? (qlo ? xp[0][r2] : xq2[0][r2]) : (qlo ? xq0[0][r2] : xp[0][r2+2]);
            const float x1v= js==0 ? (qlo ? xp[1][r2] : xq2[1][r2]) : (qlo ? xq0[1][r2] : xp[1][r2+2]);
            const float x2 = js==0 ? (qlo ? xp[2][r2] : xq2[2][r2]) : (qlo ? xq0[2][r2] : xp[2][r2+2]);
            const float x3 = js==0 ? (qlo ? xp[3][r2] : xq2[3][r2]) : (qlo ? xq0[3][r2] : xp[3][r2+2]);
            float& cst = r2 ? cst1 : cst0;
            cst = fsig(a1+x1v)*cst + fsig(a0+x0)*ftanh(a2+x2);
            hr[t&15][brow+r2][colw] = (half_t)(fsig(a3+x3)*ftanh(cst));
          }
          __syncthreads();
        }
      }
      // bulk store this block's h to hs0, then publish (release)
      {
        const int hS = tid>>5, hR = (tid>>2)&7, hC = (tid&3)*32;
        if (hS < cnt) {
          half_t* dst = hs0 + ((size_t)(bs+hS)*NMB + nm0 + hR)*128 + hC;
          #pragma unroll
          for (int k=0;k<4;k++) *(half8*)(dst + k*8) = *(const half8*)&hr[(bs+hS)&15][hR][hC + k*8];
        }
      }
      __syncthreads();
      if (tid == 0)
        __hip_atomic_store(flag, b+1, __ATOMIC_RELEASE, __HIP_MEMORY_SCOPE_AGENT);
    }
  } else {
    // ================= layer-1 consumer (8 rows) + FC/softmax ====================
    auto xs = (half_t (*)[BS][8][144])smem;           // [2][16][8][144] = 73728 B
    auto h2 = (half_t (*)[8][144])(smem + 73728);     // [2][8][144]     =  4608 B
    float* logits_lds = (float*)(smem + 78336);       // 480 f32 = 1920 B
    const int wg  = blockIdx.x - 128;
    const int nm0 = wg*8;
    const int* flag = flags + wg*16;

    for (int i=tid; i<2*8*144; i+=512) (&h2[0][0][0])[i] = (half_t)0.f;

    half8 whF[4][4], wxF[4][4]; float bias[4];
    #pragma unroll
    for (int nt=0; nt<4; nt++) {
      const int gcol = nt*128 + colw;
      #pragma unroll
      for (int kc=0; kc<4; kc++) {
        wxF[nt][kc] = load_w8(wih1 + gcol*128 + kc*32 + quad*8); pin(wxF[nt][kc]);
        whF[nt][kc] = load_w8(whh1 + gcol*128 + kc*32 + quad*8); pin(whF[nt][kc]);
      }
      bias[nt] = bih1[gcol] + bhh1[gcol];
    }
    float cst0 = 0.f, cst1 = 0.f;
    floatx4 z4 = {0.f,0.f,0.f,0.f}; pinf(z4);

    // stage mapping: thread -> (step, row, 32-col strip) ; 4 x float4 per thread
    const int sS = tid>>5, sR = (tid>>2)&7, sC = (tid&3)*32;
    float4 ld[4];
    wait_flag(flag, 1, tid);
    { const half_t* src = hs0 + ((size_t)sS*NMB + nm0 + sR)*128 + sC;
      #pragma unroll
      for (int k=0;k<4;k++) ld[k] = *(const float4*)(src + k*8); }
    #pragma unroll
    for (int k=0;k<4;k++) *(half8*)&xs[0][sS][sR][sC + k*8] = __builtin_bit_cast(half8, ld[k]);
    __syncthreads();

    for (int b=0; b<NBLK; b++) {
      const int bs = b*BS, buf = b&1;
      const int cnt = (T_STEPS - bs < BS) ? (T_STEPS - bs) : BS;
      const int ngr = cnt>>1;
      if (b+1 < NBLK) {
        wait_flag(flag, b+2, tid);
        int tt = bs + BS + sS; if (tt > 299) tt = 299;
        const half_t* src = hs0 + ((size_t)tt*NMB + nm0 + sR)*128 + sC;
        #pragma unroll
        for (int k=0;k<4;k++) ld[k] = *(const float4*)(src + k*8);
      }
      for (int g=0; g<ngr; g++) {
        const int s0 = g*2;
        floatx4 xp[4];
        {
          const half_t* xrow = &xs[buf][s0 + (l16>>3)][l16&7][0];
          #pragma unroll
          for (int nt=0; nt<4; nt++) xp[nt] = (floatx4){bias[nt],bias[nt],bias[nt],bias[nt]};
          #pragma unroll
          for (int kc=0; kc<4; kc++) {
            const half8 xa = *(const half8*)(xrow + kc*32 + quad*8);
            #pragma unroll
            for (int nt=0; nt<4; nt++)
              xp[nt] = __builtin_amdgcn_mfma_f32_16x16x32_f16(xa, wxF[nt][kc], xp[nt], 0,0,0);
          }
        }
        float xq0[4][2], xq2[4][2];
        #pragma unroll
        for (int nt=0; nt<4; nt++)
          #pragma unroll
          for (int r2=0; r2<2; r2++) {
            xq0[nt][r2] = __shfl_xor(xp[nt][r2],   32);
            xq2[nt][r2] = __shfl_xor(xp[nt][r2+2], 32);
          }
        #pragma unroll
        for (int js=0; js<2; js++) {
          const int t = bs + s0 + js;
          if (js==1 && g==0 && b+1 < NBLK) {
            #pragma unroll
            for (int k=0;k<4;k++) *(half8*)&xs[buf^1][sS][sR][sC + k*8] = __builtin_bit_cast(half8, ld[k]);
          }
          floatx4 ah[4];
          #pragma unroll
          for (int nt=0; nt<4; nt++) ah[nt] = z4;
          {
            const half_t* hrow = &h2[t&1][l16&7][0];
            #pragma unroll
            for (int kc=0; kc<4; kc++) {
              const half8 ha = *(const half8*)(hrow + kc*32 + quad*8);
              #pragma unroll
              for (int nt=0; nt<4; nt++)
                ah[nt] = __builtin_amdgcn_mfma_f32_16x16x32_f16(ha, whF[nt][kc], ah[nt], 0,0,0);
            }
          }
          #pragma unroll
          for (int r2=0; r2<2; r2++) {
            const float a0 = qlo ? ah[0][r2] : ah[0][r2+2];
            const float a1 = qlo ? ah[1][r2] : ah[1][r2+2];
            const float a2 = qlo ? ah[2][r2] : ah[2][r2+2];
            const float a3 = qlo ? ah[3][r2] : ah[3][r2+2];
            const float x0 = js==0 ? (qlo ? xp[0][r2] : xq2[0][r2]) : (qlo ? xq0[0][r2] : xp[0][r2+2]);
            const float x1v= js==0 ? (qlo ? xp[1][r2] : xq2[1][r2]) : (qlo ? xq0[1][r2] : xp[1][r2+2]);
            const float x2 = js==0 ? (qlo ? xp[2][r2] : xq2[2][r2]) : (qlo ? xq0[2][r2] : xp[2][r2+2]);
            const float x3 = js==0 ? (qlo ? xp[3][r2] : xq2[3][r2]) : (qlo ? xq0[3][r2] : xp[3][r2+2]);
            float& cst = r2 ? cst1 : cst0;
            cst = fsig(a1+x1v)*cst + fsig(a0+x0)*ftanh(a2+x2);
            h2[(t+1)&1][brow+r2][colw] = (half_t)(fsig(a3+x3)*ftanh(cst));
          }
          __syncthreads();
        }
      }
    }

    // ---- FC (60 classes) + softmax; h1[299] in h2[0] rows 0..7
    if (tid < 480) {
      const int rr = tid/60, cls = tid%60;
      float s = fcb[cls];
      for (int k2=0; k2<128; k2++) s += (float)h2[0][rr][k2] * fcw[cls*128+k2];
      logits_lds[rr*60+cls] = s;
    }
    __syncthreads();
    if (tid < 8) {
      float m = -1e30f;
      for (int j=0; j<60; j++) m = fmaxf(m, logits_lds[tid*60+j]);
      float s = 0.f;
      for (int j=0; j<60; j++) s += __expf(logits_lds[tid*60+j]-m);
      const float inv = frcp(s);
      for (int j=0; j<60; j++) out[(nm0+tid)*60+j] = __expf(logits_lds[tid*60+j]-m)*inv;
    }
  }
}

extern "C" void kernel_launch(void* const* d_in, const int* in_sizes, int n_in,
                              void* d_out, int out_size, void* d_ws, size_t ws_size,
                              hipStream_t stream) {
  const float* x1      = (const float*)d_in[0];
  const float* cheb_w0 = (const float*)d_in[2];
  const float* cheb_w1 = (const float*)d_in[3];
  const float* cheb_b  = (const float*)d_in[4];
  const float* wih0    = (const float*)d_in[5];
  const float* whh0    = (const float*)d_in[6];
  const float* bih0    = (const float*)d_in[7];
  const float* bhh0    = (const float*)d_in[8];
  const float* wih1    = (const float*)d_in[9];
  const float* whh1    = (const float*)d_in[10];
  const float* bih1    = (const float*)d_in[11];
  const float* bhh1    = (const float*)d_in[12];
  const float* fc_w    = (const float*)d_in[13];
  const float* fc_b    = (const float*)d_in[14];

  char* ws = (char*)d_ws;
  half_t* hs0   = (half_t*)(ws + HS0_OFF);
  half_t* wch   = (half_t*)(ws + WCH_OFF);
  float*  biasc = (float*)(ws + BC_OFF);
  int*    flags = (int*)(ws + FLAG_OFF);

  k_prep<<<dim3(1), dim3(512), 0, stream>>>(cheb_w0, cheb_w1, cheb_b, wih0, bih0, bhh0, wch, biasc, flags);
  k_lstm_fused<<<dim3(256), dim3(512), 0, stream>>>(
      x1, wch, biasc, whh0, hs0, wih1, whh1, bih1, bhh1, fc_w, fc_b, (float*)d_out, flags);
}

// Round 6
// 430.347 us; speedup vs baseline: 2.7983x; 1.0649x over previous
//
#include <hip/hip_runtime.h>
#include <hip/hip_fp16.h>

typedef _Float16 half_t;
typedef _Float16 half8 __attribute__((ext_vector_type(8)));
typedef float floatx4 __attribute__((ext_vector_type(4)));
typedef int   int4v  __attribute__((ext_vector_type(4)));

// ---- sizes ----
#define T_STEPS 300
#define NMB     1024                 // N*M batch
#define BS      16                   // steps per staged block
#define NBLK    19                   // ceil(300/16)

// LDS pitches: row stride must be != 8 dwords (mod 32) to avoid 4-way bank
// conflicts on b128 A-frag reads. 12 mod 32 gives 8 distinct start banks.
#define XP0 88                       // producer x row pitch (halfs): 176B = 44 dw = 12 mod 32
#define HP  152                      // h row pitch (halfs): 304B = 76 dw = 12 mod 32

// ws layout (bytes)
#define XT_OFF   0ULL
#define XT_BYTES ((unsigned long long)(T_STEPS*NMB + 16)*64*2)
#define HS0_OFF  (XT_OFF + XT_BYTES)
#define HS0_BYTES ((unsigned long long)(T_STEPS*NMB + 16)*128*2)
#define WCH_OFF  (HS0_OFF + HS0_BYTES)        // wcomb as f16 [512][64]
#define WCH_BYTES (512ULL*64*2)
#define BC_OFF   (WCH_OFF + WCH_BYTES)        // biasc f32 [512]
#define BC_BYTES (512ULL*4)
#define FLAG_OFF (BC_OFF + BC_BYTES)          // flags, 64B stride

// L_hat = -D^-1/2 A D^-1/2 for the hardcoded 15-node skeleton (row=dst, col=src)
#define S2 0.70710678118654752f
#define QH 0.5f
#define UU 0.40824829046386302f
#define TH 0.33333333333333333f
__constant__ float LHAT[225] = {
  0,0,-S2,0,0,0,0,0,0,0,0,0,0,0,0,
  0,0,0,-S2,0,0,0,0,0,0,0,0,0,0,0,
  -S2,0,0,0,-QH,0,0,0,0,0,0,0,0,0,0,
  0,-S2,0,0,0,-QH,0,0,0,0,0,0,0,0,0,
  0,0,-QH,0,0,0,0,0,0,0,0,0,0,0,-UU,
  0,0,0,-QH,0,0,0,0,0,0,0,0,0,0,-UU,
  0,0,0,0,0,0,0,0,-S2,0,0,0,0,0,0,
  0,0,0,0,0,0,0,0,0,-S2,0,0,0,0,0,
  0,0,0,0,0,0,-S2,0,0,0,-QH,0,0,0,0,
  0,0,0,0,0,0,0,-S2,0,0,0,-QH,0,0,0,
  0,0,0,0,0,0,0,0,-QH,0,0,0,0,-UU,0,
  0,0,0,0,0,0,0,0,0,-QH,0,0,0,-UU,0,
  0,0,0,0,0,0,0,0,0,0,0,0,0,0,0,
  0,0,0,0,0,0,0,0,0,0,-UU,-UU,0,0,0,
  0,0,0,0,-UU,-UU,0,0,0,0,0,0,0,-TH,0
};

// Fast gate math: v_exp_f32 + v_rcp_f32 (approx, ~1 ulp).
__device__ __forceinline__ float frcp(float x)  { return __builtin_amdgcn_rcpf(x); }
__device__ __forceinline__ float fsig(float x)  { return frcp(1.f + __expf(-x)); }
__device__ __forceinline__ float ftanh(float x) { return 2.f*frcp(1.f + __expf(-2.f*x)) - 1.f; }

__device__ __forceinline__ half8 load_w8(const float* p) {
  const float4* q = (const float4*)p;
  float4 a = q[0], b = q[1];
  half8 f;
  f[0]=(half_t)a.x; f[1]=(half_t)a.y; f[2]=(half_t)a.z; f[3]=(half_t)a.w;
  f[4]=(half_t)b.x; f[5]=(half_t)b.y; f[6]=(half_t)b.z; f[7]=(half_t)b.w;
  return f;
}

// Force true register residency of weight fragments (kills per-step remat).
__device__ __forceinline__ void pin(half8& f) {
  int4v t = __builtin_bit_cast(int4v, f);
  asm volatile("" : "+v"(t));
  f = __builtin_bit_cast(half8, t);
}
__device__ __forceinline__ void pinf(floatx4& f) {
  int4v t = __builtin_bit_cast(int4v, f);
  asm volatile("" : "+v"(t));
  f = __builtin_bit_cast(floatx4, t);
}

// Consumer-side block gate: relaxed poll + one acquire.
__device__ __forceinline__ void wait_flag(const int* f, int want, int tid) {
  if (tid == 0) {
    while (__hip_atomic_load(f, __ATOMIC_RELAXED, __HIP_MEMORY_SCOPE_AGENT) < want)
      __builtin_amdgcn_s_sleep(8);
    (void)__hip_atomic_load(f, __ATOMIC_ACQUIRE, __HIP_MEMORY_SCOPE_AGENT);
  }
  __syncthreads();
}

// ---- K0: fold ChebConv into layer-0 input projection: wcomb_h f16[512][64], biasc[512]
// Also zeroes the producer->consumer block flags (must happen every replay).
__global__ void k_prep(const float* __restrict__ w0, const float* __restrict__ w1,
                       const float* __restrict__ cb, const float* __restrict__ wih0,
                       const float* __restrict__ bih0, const float* __restrict__ bhh0,
                       half_t* __restrict__ wcomb_h, float* __restrict__ biasc,
                       int* __restrict__ flags) {
  const int n = threadIdx.x; // 512 threads, 1 block
  if (n < 256) flags[n*16] = 0;
  float wrow[45];
  #pragma unroll
  for (int i=0;i<45;i++) wrow[i] = wih0[n*45+i];
  float P[45];
  #pragma unroll
  for (int i=0;i<15;i++)
    #pragma unroll
    for (int c=0;c<3;c++) {
      float s = 0.f;
      #pragma unroll
      for (int cp=0;cp<3;cp++) s += wrow[i*3+cp]*w1[cp*3+c];
      P[i*3+c] = s;
    }
  #pragma unroll
  for (int j=0;j<15;j++)
    #pragma unroll
    for (int c=0;c<3;c++) {
      float s = 0.f;
      #pragma unroll
      for (int cp=0;cp<3;cp++) s += wrow[j*3+cp]*w0[cp*3+c];
      #pragma unroll
      for (int i=0;i<15;i++) s += LHAT[i*15+j]*P[i*3+c];
      wcomb_h[n*64 + j*3+c] = (half_t)s;
    }
  for (int k=45;k<64;k++) wcomb_h[n*64+k] = (half_t)0.f;
  float b = bih0[n] + bhh0[n];
  #pragma unroll
  for (int i=0;i<15;i++)
    #pragma unroll
    for (int cp=0;cp<3;cp++) b += wrow[i*3+cp]*cb[cp];
  biasc[n] = b;
}

// ---- Fused LSTM on DISJOINT CUs (structure proven in R5). Grid 256 x 512, 1 WG/CU.
// Blocks 0..127 = layer-0 producers (inline x1 transpose), 128..255 = layer-1
// consumers (+FC/softmax); hs0 handoff via L2 (block w and w+128 share an XCD).
//
// R6 changes (latency/VALU diet, mapping is the point):
//  * BATCH-MAJOR A rows for the 2-step xproj group: A row m = batch(m>>1), js(m&1).
//    With the h-chain A row m = h[batch m>>1] (hr read at [l16>>1]), C reg r at
//    lane (quad,l16) is batch 2q+(r>>1), step r&1 for BOTH ah and xp ->
//    gates are ah[nt][bb*2+js] + xp[nt][bb*2+js], ALL STATIC. No shfl_xor, no
//    cndmask select trees (was 8 ds-ops + 16 selects per step).
//  * LDS row pitches 12 dwords mod 32 (x: 88 halfs, h: 152 halfs): A-frag b128
//    reads get 8 distinct start banks (was 4-way conflict), h-chain reads
//    conflict-free.
//  * Producer staging decode via bit ops (pad v to 16 slots), no %15 chains.
__launch_bounds__(512, 1)
__global__ void k_lstm_fused(const float* __restrict__ x1, const half_t* __restrict__ wch,
                             const float* __restrict__ biasc, const float* __restrict__ whh0,
                             half_t* __restrict__ hs0,
                             const float* __restrict__ wih1, const float* __restrict__ whh1,
                             const float* __restrict__ bih1, const float* __restrict__ bhh1,
                             const float* __restrict__ fcw, const float* __restrict__ fcb,
                             float* __restrict__ out, int* __restrict__ flags) {
  __shared__ __align__(16) char smem[84640];
  const int tid = threadIdx.x;
  const int wave = tid>>6, lane = tid&63, quad = lane>>4, l16 = lane&15;
  const int colw = wave*16 + l16;              // owned h column (0..127)

  if (blockIdx.x < 128) {
    // ================= layer-0 producer (8 rows, inline x-transpose) =============
    auto xs = (half_t (*)[BS][8][XP0])smem;             // [2][16][8][88] = 45056 B
    auto hr = (half_t (*)[8][HP])(smem + 45056);        // [16][8][152]   = 38912 B
    const int wg  = blockIdx.x;
    const int nm0 = wg*8;
    const int n0t3 = wg*4*3;                            // (n0)*3 for x1 addressing
    int* flag = flags + wg*16;

    // zero xs once (cols 45..87 never written; must be 0 for MFMA A)
    for (int i=tid; i<2*BS*8*XP0; i+=512) ((half_t*)smem)[i] = (half_t)0.f;
    for (int i=tid; i<8*HP; i+=512) (&hr[15][0][0])[i] = (half_t)0.f;

    half8 whhF[4][4]; half8 wcF[4][2]; float bias[4];
    #pragma unroll
    for (int nt=0; nt<4; nt++) {
      const int gcol = nt*128 + colw;
      #pragma unroll
      for (int kc=0; kc<4; kc++) { whhF[nt][kc] = load_w8(whh0 + gcol*128 + kc*32 + quad*8); pin(whhF[nt][kc]); }
      #pragma unroll
      for (int kc=0; kc<2; kc++) { wcF[nt][kc] = *(const half8*)(wch + gcol*64 + kc*32 + quad*8); pin(wcF[nt][kc]); }
      bias[nt] = biasc[gcol];
    }
    float cst0 = 0.f, cst1 = 0.f;
    floatx4 z4 = {0.f,0.f,0.f,0.f}; pinf(z4);

    // x staging via 3072 virtual slots: idx = k*512+tid; v=idx&15 (skip 15),
    // sh=(idx>>4)&15, rB=idx>>8 (= nh*3+c, 0..11). Pure bit-op decode.
    float2 xld[6];
    #define XLOAD(TBASE) { _Pragma("unroll") for (int k=0;k<6;k++) {          \
        const int idx=k*512+tid; const int v_=idx&15;                          \
        if (v_<15) { const int sh_=(idx>>4)&15; const int rB_=idx>>8;          \
          int tt=(TBASE)+sh_; if (tt>299) tt=299;                              \
          xld[k]=((const float2*)x1)[(size_t)((n0t3+rB_)*300+tt)*15+v_]; } } }
    #define XWRITE(BUFI) { _Pragma("unroll") for (int k=0;k<6;k++) {          \
        const int idx=k*512+tid; const int v_=idx&15;                          \
        if (v_<15) { const int sh_=(idx>>4)&15; const int rB_=idx>>8;          \
          const int nh_=rB_/3, c_=rB_-3*(rB_/3);                               \
          xs[BUFI][sh_][nh_*2  ][v_*3+c_]=(half_t)xld[k].x;                    \
          xs[BUFI][sh_][nh_*2+1][v_*3+c_]=(half_t)xld[k].y; } } }

    XLOAD(0); __syncthreads(); XWRITE(0);   // zero-fill of xs must precede writes
    __syncthreads();

    for (int b=0; b<NBLK; b++) {
      const int bs = b*BS, buf = b&1;
      const int cnt = (T_STEPS - bs < BS) ? (T_STEPS - bs) : BS;
      const int ngr = cnt>>1;                 // 2-step groups
      if (b+1 < NBLK) XLOAD(bs + BS);
      for (int g=0; g<ngr; g++) {
        const int s0 = g*2;
        // ---- batched xproj, A row = batch*2 + js (batch-major), bias in C-init
        floatx4 xp[4];
        {
          const half_t* xrow = &xs[buf][s0 + (l16&1)][l16>>1][0];
          #pragma unroll
          for (int nt=0; nt<4; nt++) xp[nt] = (floatx4){bias[nt],bias[nt],bias[nt],bias[nt]};
          #pragma unroll
          for (int kc=0; kc<2; kc++) {
            const half8 xa = *(const half8*)(xrow + kc*32 + quad*8);
            #pragma unroll
            for (int nt=0; nt<4; nt++)
              xp[nt] = __builtin_amdgcn_mfma_f32_16x16x32_f16(xa, wcF[nt][kc], xp[nt], 0,0,0);
          }
        }
        #pragma unroll
        for (int js=0; js<2; js++) {
          const int t = bs + s0 + js;
          if (js==1 && g==0 && b+1 < NBLK) XWRITE(buf^1);
          // recurrent h-chain; A row m = h[batch m>>1] so C regs align with xp
          floatx4 ah[4];
          #pragma unroll
          for (int nt=0; nt<4; nt++) ah[nt] = z4;
          {
            const half_t* hrow = &hr[(t+15)&15][l16>>1][0];
            #pragma unroll
            for (int kc=0; kc<4; kc++) {
              const half8 ha = *(const half8*)(hrow + kc*32 + quad*8);
              #pragma unroll
              for (int nt=0; nt<4; nt++)
                ah[nt] = __builtin_amdgcn_mfma_f32_16x16x32_f16(ha, whhF[nt][kc], ah[nt], 0,0,0);
            }
          }
          #pragma unroll
          for (int bb=0; bb<2; bb++) {
            const int r = bb*2 + js;           // static after unroll
            const float gi = ah[0][r] + xp[0][r];
            const float gf = ah[1][r] + xp[1][r];
            const float gg = ah[2][r] + xp[2][r];
            const float go = ah[3][r] + xp[3][r];
            float& cst = bb ? cst1 : cst0;
            cst = fsig(gf)*cst + fsig(gi)*ftanh(gg);
            hr[t&15][quad*2+bb][colw] = (half_t)(fsig(go)*ftanh(cst));
          }
          __syncthreads();
        }
      }
      // bulk store this block's h to hs0, then publish (release)
      {
        const int hS = tid>>5, hR = (tid>>2)&7, hC = (tid&3)*32;
        if (hS < cnt) {
          half_t* dst = hs0 + ((size_t)(bs+hS)*NMB + nm0 + hR)*128 + hC;
          #pragma unroll
          for (int k=0;k<4;k++) *(half8*)(dst + k*8) = *(const half8*)&hr[(bs+hS)&15][hR][hC + k*8];
        }
      }
      __syncthreads();
      if (tid == 0)
        __hip_atomic_store(flag, b+1, __ATOMIC_RELEASE, __HIP_MEMORY_SCOPE_AGENT);
    }
  } else {
    // ================= layer-1 consumer (8 rows) + FC/softmax ====================
    auto xs = (half_t (*)[BS][8][HP])smem;              // [2][16][8][152] = 77824 B
    auto h2 = (half_t (*)[8][HP])(smem + 77824);        // [2][8][152]     =  4864 B
    float* logits_lds = (float*)(smem + 82688);         // 480 f32 = 1920 B
    const int wg  = blockIdx.x - 128;
    const int nm0 = wg*8;
    const int* flag = flags + wg*16;

    for (int i=tid; i<2*8*HP; i+=512) (&h2[0][0][0])[i] = (half_t)0.f;

    half8 whF[4][4], wxF[4][4]; float bias[4];
    #pragma unroll
    for (int nt=0; nt<4; nt++) {
      const int gcol = nt*128 + colw;
      #pragma unroll
      for (int kc=0; kc<4; kc++) {
        wxF[nt][kc] = load_w8(wih1 + gcol*128 + kc*32 + quad*8); pin(wxF[nt][kc]);
        whF[nt][kc] = load_w8(whh1 + gcol*128 + kc*32 + quad*8); pin(whF[nt][kc]);
      }
      bias[nt] = bih1[gcol] + bhh1[gcol];
    }
    float cst0 = 0.f, cst1 = 0.f;
    floatx4 z4 = {0.f,0.f,0.f,0.f}; pinf(z4);

    // stage mapping: thread -> (step, row, 32-col strip); 4 x float4 per thread
    const int sS = tid>>5, sR = (tid>>2)&7, sC = (tid&3)*32;
    float4 ld[4];
    wait_flag(flag, 1, tid);
    { const half_t* src = hs0 + ((size_t)sS*NMB + nm0 + sR)*128 + sC;
      #pragma unroll
      for (int k=0;k<4;k++) ld[k] = *(const float4*)(src + k*8); }
    #pragma unroll
    for (int k=0;k<4;k++) *(half8*)&xs[0][sS][sR][sC + k*8] = __builtin_bit_cast(half8, ld[k]);
    __syncthreads();

    for (int b=0; b<NBLK; b++) {
      const int bs = b*BS, buf = b&1;
      const int cnt = (T_STEPS - bs < BS) ? (T_STEPS - bs) : BS;
      const int ngr = cnt>>1;
      if (b+1 < NBLK) {
        wait_flag(flag, b+2, tid);
        int tt = bs + BS + sS; if (tt > 299) tt = 299;
        const half_t* src = hs0 + ((size_t)tt*NMB + nm0 + sR)*128 + sC;
        #pragma unroll
        for (int k=0;k<4;k++) ld[k] = *(const float4*)(src + k*8);
      }
      for (int g=0; g<ngr; g++) {
        const int s0 = g*2;
        // ---- batched xproj (batch-major rows), bias in C-init
        floatx4 xp[4];
        {
          const half_t* xrow = &xs[buf][s0 + (l16&1)][l16>>1][0];
          #pragma unroll
          for (int nt=0; nt<4; nt++) xp[nt] = (floatx4){bias[nt],bias[nt],bias[nt],bias[nt]};
          #pragma unroll
          for (int kc=0; kc<4; kc++) {
            const half8 xa = *(const half8*)(xrow + kc*32 + quad*8);
            #pragma unroll
            for (int nt=0; nt<4; nt++)
              xp[nt] = __builtin_amdgcn_mfma_f32_16x16x32_f16(xa, wxF[nt][kc], xp[nt], 0,0,0);
          }
        }
        #pragma unroll
        for (int js=0; js<2; js++) {
          const int t = bs + s0 + js;
          if (js==1 && g==0 && b+1 < NBLK) {
            #pragma unroll
            for (int k=0;k<4;k++) *(half8*)&xs[buf^1][sS][sR][sC + k*8] = __builtin_bit_cast(half8, ld[k]);
          }
          floatx4 ah[4];
          #pragma unroll
          for (int nt=0; nt<4; nt++) ah[nt] = z4;
          {
            const half_t* hrow = &h2[t&1][l16>>1][0];
            #pragma unroll
            for (int kc=0; kc<4; kc++) {
              const half8 ha = *(const half8*)(hrow + kc*32 + quad*8);
              #pragma unroll
              for (int nt=0; nt<4; nt++)
                ah[nt] = __builtin_amdgcn_mfma_f32_16x16x32_f16(ha, whF[nt][kc], ah[nt], 0,0,0);
            }
          }
          #pragma unroll
          for (int bb=0; bb<2; bb++) {
            const int r = bb*2 + js;
            const float gi = ah[0][r] + xp[0][r];
            const float gf = ah[1][r] + xp[1][r];
            const float gg = ah[2][r] + xp[2][r];
            const float go = ah[3][r] + xp[3][r];
            float& cst = bb ? cst1 : cst0;
            cst = fsig(gf)*cst + fsig(gi)*ftanh(gg);
            h2[(t+1)&1][quad*2+bb][colw] = (half_t)(fsig(go)*ftanh(cst));
          }
          __syncthreads();
        }
      }
    }

    // ---- FC (60 classes) + softmax; h1[299] in h2[0] rows 0..7
    if (tid < 480) {
      const int rr = tid/60, cls = tid%60;
      float s = fcb[cls];
      for (int k2=0; k2<128; k2++) s += (float)h2[0][rr][k2] * fcw[cls*128+k2];
      logits_lds[rr*60+cls] = s;
    }
    __syncthreads();
    if (tid < 8) {
      float m = -1e30f;
      for (int j=0; j<60; j++) m = fmaxf(m, logits_lds[tid*60+j]);
      float s = 0.f;
      for (int j=0; j<60; j++) s += __expf(logits_lds[tid*60+j]-m);
      const float inv = frcp(s);
      for (int j=0; j<60; j++) out[(nm0+tid)*60+j] = __expf(logits_lds[tid*60+j]-m)*inv;
    }
  }
}

extern "C" void kernel_launch(void* const* d_in, const int* in_sizes, int n_in,
                              void* d_out, int out_size, void* d_ws, size_t ws_size,
                              hipStream_t stream) {
  const float* x1      = (const float*)d_in[0];
  const float* cheb_w0 = (const float*)d_in[2];
  const float* cheb_w1 = (const float*)d_in[3];
  const float* cheb_b  = (const float*)d_in[4];
  const float* wih0    = (const float*)d_in[5];
  const float* whh0    = (const float*)d_in[6];
  const float* bih0    = (const float*)d_in[7];
  const float* bhh0    = (const float*)d_in[8];
  const float* wih1    = (const float*)d_in[9];
  const float* whh1    = (const float*)d_in[10];
  const float* bih1    = (const float*)d_in[11];
  const float* bhh1    = (const float*)d_in[12];
  const float* fc_w    = (const float*)d_in[13];
  const float* fc_b    = (const float*)d_in[14];

  char* ws = (char*)d_ws;
  half_t* hs0   = (half_t*)(ws + HS0_OFF);
  half_t* wch   = (half_t*)(ws + WCH_OFF);
  float*  biasc = (float*)(ws + BC_OFF);
  int*    flags = (int*)(ws + FLAG_OFF);

  k_prep<<<dim3(1), dim3(512), 0, stream>>>(cheb_w0, cheb_w1, cheb_b, wih0, bih0, bhh0, wch, biasc, flags);
  k_lstm_fused<<<dim3(256), dim3(512), 0, stream>>>(
      x1, wch, biasc, whh0, hs0, wih1, whh1, bih1, bhh1, fc_w, fc_b, (float*)d_out, flags);
}

// Round 7
// 429.008 us; speedup vs baseline: 2.8070x; 1.0031x over previous
//
#include <hip/hip_runtime.h>
#include <hip/hip_fp16.h>

typedef _Float16 half_t;
typedef _Float16 half8 __attribute__((ext_vector_type(8)));
typedef float floatx4 __attribute__((ext_vector_type(4)));
typedef int   int4v  __attribute__((ext_vector_type(4)));

// ---- sizes ----
#define T_STEPS 300
#define NMB     1024                 // N*M batch
#define BS      16                   // steps per staged block
#define NBLK    19                   // ceil(300/16)

// LDS geometry. Row pitch 12 dw mod 32 (8 start bank-groups); step-group stride
// gets +8 halfs pad so it is 4 mod 32 dw (R6 bug: 0 mod 32 -> l16&1 step-aliasing
// made x-reads 8-touch per bank group, SQ_LDS_BANK_CONFLICT 14.6M).
#define XP0   88                     // producer x row pitch (halfs): 44 dw = 12 mod 32
#define XROW0 (8*XP0 + 8)            // 712: step stride 356 dw = 4 mod 32, 16B-aligned
#define HP    152                    // h row pitch (halfs): 76 dw = 12 mod 32
#define XROW1 (8*HP + 8)             // 1224: step stride 612 dw = 4 mod 32
#define HSLOT (8*HP)                 // 1216 halfs per h ring slot

// ws layout (bytes)
#define XT_OFF   0ULL
#define XT_BYTES ((unsigned long long)(T_STEPS*NMB + 16)*64*2)
#define HS0_OFF  (XT_OFF + XT_BYTES)
#define HS0_BYTES ((unsigned long long)(T_STEPS*NMB + 16)*128*2)
#define WCH_OFF  (HS0_OFF + HS0_BYTES)        // wcomb as f16 [512][64]
#define WCH_BYTES (512ULL*64*2)
#define BC_OFF   (WCH_OFF + WCH_BYTES)        // biasc f32 [512]
#define BC_BYTES (512ULL*4)
#define FLAG_OFF (BC_OFF + BC_BYTES)          // flags, 64B stride

// L_hat = -D^-1/2 A D^-1/2 for the hardcoded 15-node skeleton (row=dst, col=src)
#define S2 0.70710678118654752f
#define QH 0.5f
#define UU 0.40824829046386302f
#define TH 0.33333333333333333f
__constant__ float LHAT[225] = {
  0,0,-S2,0,0,0,0,0,0,0,0,0,0,0,0,
  0,0,0,-S2,0,0,0,0,0,0,0,0,0,0,0,
  -S2,0,0,0,-QH,0,0,0,0,0,0,0,0,0,0,
  0,-S2,0,0,0,-QH,0,0,0,0,0,0,0,0,0,
  0,0,-QH,0,0,0,0,0,0,0,0,0,0,0,-UU,
  0,0,0,-QH,0,0,0,0,0,0,0,0,0,0,-UU,
  0,0,0,0,0,0,0,0,-S2,0,0,0,0,0,0,
  0,0,0,0,0,0,0,0,0,-S2,0,0,0,0,0,
  0,0,0,0,0,0,-S2,0,0,0,-QH,0,0,0,0,
  0,0,0,0,0,0,0,-S2,0,0,0,-QH,0,0,0,
  0,0,0,0,0,0,0,0,-QH,0,0,0,0,-UU,0,
  0,0,0,0,0,0,0,0,0,-QH,0,0,0,-UU,0,
  0,0,0,0,0,0,0,0,0,0,0,0,0,0,0,
  0,0,0,0,0,0,0,0,0,0,-UU,-UU,0,0,0,
  0,0,0,0,-UU,-UU,0,0,0,0,0,0,0,-TH,0
};

// Fast gate math: v_exp_f32 + v_rcp_f32 (approx, ~1 ulp).
__device__ __forceinline__ float frcp(float x)  { return __builtin_amdgcn_rcpf(x); }
__device__ __forceinline__ float fsig(float x)  { return frcp(1.f + __expf(-x)); }
__device__ __forceinline__ float ftanh(float x) { return 2.f*frcp(1.f + __expf(-2.f*x)) - 1.f; }

__device__ __forceinline__ half8 load_w8(const float* p) {
  const float4* q = (const float4*)p;
  float4 a = q[0], b = q[1];
  half8 f;
  f[0]=(half_t)a.x; f[1]=(half_t)a.y; f[2]=(half_t)a.z; f[3]=(half_t)a.w;
  f[4]=(half_t)b.x; f[5]=(half_t)b.y; f[6]=(half_t)b.z; f[7]=(half_t)b.w;
  return f;
}

// Force true register residency of fragments (kills per-step remat).
__device__ __forceinline__ void pin(half8& f) {
  int4v t = __builtin_bit_cast(int4v, f);
  asm volatile("" : "+v"(t));
  f = __builtin_bit_cast(half8, t);
}
__device__ __forceinline__ void pinf(floatx4& f) {
  int4v t = __builtin_bit_cast(int4v, f);
  asm volatile("" : "+v"(t));
  f = __builtin_bit_cast(floatx4, t);
}

// Consumer-side block gate: relaxed poll + one acquire.
__device__ __forceinline__ void wait_flag(const int* f, int want, int tid) {
  if (tid == 0) {
    while (__hip_atomic_load(f, __ATOMIC_RELAXED, __HIP_MEMORY_SCOPE_AGENT) < want)
      __builtin_amdgcn_s_sleep(8);
    (void)__hip_atomic_load(f, __ATOMIC_ACQUIRE, __HIP_MEMORY_SCOPE_AGENT);
  }
  __syncthreads();
}

// ---- K0: fold ChebConv into layer-0 input projection: wcomb_h f16[512][64], biasc[512]
// Also zeroes the producer->consumer block flags (must happen every replay).
__global__ void k_prep(const float* __restrict__ w0, const float* __restrict__ w1,
                       const float* __restrict__ cb, const float* __restrict__ wih0,
                       const float* __restrict__ bih0, const float* __restrict__ bhh0,
                       half_t* __restrict__ wcomb_h, float* __restrict__ biasc,
                       int* __restrict__ flags) {
  const int n = threadIdx.x; // 512 threads, 1 block
  if (n < 256) flags[n*16] = 0;
  float wrow[45];
  #pragma unroll
  for (int i=0;i<45;i++) wrow[i] = wih0[n*45+i];
  float P[45];
  #pragma unroll
  for (int i=0;i<15;i++)
    #pragma unroll
    for (int c=0;c<3;c++) {
      float s = 0.f;
      #pragma unroll
      for (int cp=0;cp<3;cp++) s += wrow[i*3+cp]*w1[cp*3+c];
      P[i*3+c] = s;
    }
  #pragma unroll
  for (int j=0;j<15;j++)
    #pragma unroll
    for (int c=0;c<3;c++) {
      float s = 0.f;
      #pragma unroll
      for (int cp=0;cp<3;cp++) s += wrow[j*3+cp]*w0[cp*3+c];
      #pragma unroll
      for (int i=0;i<15;i++) s += LHAT[i*15+j]*P[i*3+c];
      wcomb_h[n*64 + j*3+c] = (half_t)s;
    }
  for (int k=45;k<64;k++) wcomb_h[n*64+k] = (half_t)0.f;
  float b = bih0[n] + bhh0[n];
  #pragma unroll
  for (int i=0;i<15;i++)
    #pragma unroll
    for (int cp=0;cp<3;cp++) b += wrow[i*3+cp]*cb[cp];
  biasc[n] = b;
}

// ---- Fused LSTM on DISJOINT CUs. Grid 256 x 512, 1 WG/CU.
// Blocks 0..127 = layer-0 producers (inline x1 transpose), 128..255 = layer-1
// consumers (+FC/softmax); hs0 handoff via flags (L2-local: w and w+128 share XCD).
// R7 changes: (1) step-stride pad (see XROW0/XROW1) kills the l16&1 step-aliasing
// bank conflicts; (2) xproj folded as the h-chain MFMA C-INPUT (D!=C form, copy
// free) -> no per-gate adds, no zero-init; (3) bias held as pinned floatx4 used
// as the xproj MFMA C-input -> no per-group v_mov bias splats.
__launch_bounds__(512, 1)
__global__ void k_lstm_fused(const float* __restrict__ x1, const half_t* __restrict__ wch,
                             const float* __restrict__ biasc, const float* __restrict__ whh0,
                             half_t* __restrict__ hs0,
                             const float* __restrict__ wih1, const float* __restrict__ whh1,
                             const float* __restrict__ bih1, const float* __restrict__ bhh1,
                             const float* __restrict__ fcw, const float* __restrict__ fcb,
                             float* __restrict__ out, int* __restrict__ flags) {
  __shared__ __align__(16) char smem[85120];
  half_t* S = (half_t*)smem;
  const int tid = threadIdx.x;
  const int wave = tid>>6, lane = tid&63, quad = lane>>4, l16 = lane&15;
  const int colw = wave*16 + l16;              // owned h column (0..127)

  if (blockIdx.x < 128) {
    // ================= layer-0 producer (8 rows, inline x-transpose) =============
    half_t* XS = S;                   // [2][16][XROW0] = 22784 halfs
    half_t* HR = S + 2*BS*XROW0;      // [16][HSLOT]    = 19456 halfs
    const int wg  = blockIdx.x;
    const int nm0 = wg*8;
    const int n0t3 = wg*4*3;                            // (n0)*3 for x1 addressing
    int* flag = flags + wg*16;

    // zero xs once (cols 45..87 + pads never written; must be 0 for MFMA A)
    for (int i=tid; i<2*BS*XROW0; i+=512) XS[i] = (half_t)0.f;
    for (int i=tid; i<HSLOT; i+=512) HR[15*HSLOT + i] = (half_t)0.f;

    half8 whhF[4][4]; half8 wcF[4][2]; floatx4 biasv[4];
    #pragma unroll
    for (int nt=0; nt<4; nt++) {
      const int gcol = nt*128 + colw;
      #pragma unroll
      for (int kc=0; kc<4; kc++) { whhF[nt][kc] = load_w8(whh0 + gcol*128 + kc*32 + quad*8); pin(whhF[nt][kc]); }
      #pragma unroll
      for (int kc=0; kc<2; kc++) { wcF[nt][kc] = *(const half8*)(wch + gcol*64 + kc*32 + quad*8); pin(wcF[nt][kc]); }
      const float b = biasc[gcol];
      biasv[nt] = (floatx4){b,b,b,b}; pinf(biasv[nt]);
    }
    float cst0 = 0.f, cst1 = 0.f;

    // x staging via 3072 virtual slots: idx = k*512+tid; v=idx&15 (skip 15),
    // sh=(idx>>4)&15, rB=idx>>8 (= nh*3+c, 0..11). Pure bit-op decode.
    float2 xld[6];
    #define XLOAD(TBASE) { _Pragma("unroll") for (int k=0;k<6;k++) {          \
        const int idx=k*512+tid; const int v_=idx&15;                          \
        if (v_<15) { const int sh_=(idx>>4)&15; const int rB_=idx>>8;          \
          int tt=(TBASE)+sh_; if (tt>299) tt=299;                              \
          xld[k]=((const float2*)x1)[(size_t)((n0t3+rB_)*300+tt)*15+v_]; } } }
    #define XWRITE(BUFI) { _Pragma("unroll") for (int k=0;k<6;k++) {          \
        const int idx=k*512+tid; const int v_=idx&15;                          \
        if (v_<15) { const int sh_=(idx>>4)&15; const int rB_=idx>>8;          \
          const int nh_=rB_/3, c_=rB_-3*(rB_/3);                               \
          half_t* w = XS + ((BUFI)*BS + sh_)*XROW0 + nh_*2*XP0 + v_*3+c_;      \
          w[0]   = (half_t)xld[k].x;                                           \
          w[XP0] = (half_t)xld[k].y; } } }

    XLOAD(0); __syncthreads(); XWRITE(0);   // zero-fill of xs must precede writes
    __syncthreads();

    for (int b=0; b<NBLK; b++) {
      const int bs = b*BS, buf = b&1;
      const int cnt = (T_STEPS - bs < BS) ? (T_STEPS - bs) : BS;
      const int ngr = cnt>>1;                 // 2-step groups
      if (b+1 < NBLK) XLOAD(bs + BS);
      for (int g=0; g<ngr; g++) {
        const int s0 = g*2;
        // ---- batched xproj, A row = batch*2 + js (batch-major), C-init = biasv
        floatx4 xp[4];
        {
          const half_t* xrow = XS + (buf*BS + s0 + (l16&1))*XROW0 + (l16>>1)*XP0;
          const half8 xa0 = *(const half8*)(xrow + quad*8);
          const half8 xa1 = *(const half8*)(xrow + 32 + quad*8);
          #pragma unroll
          for (int nt=0; nt<4; nt++) {
            floatx4 a = __builtin_amdgcn_mfma_f32_16x16x32_f16(xa0, wcF[nt][0], biasv[nt], 0,0,0);
            xp[nt]    = __builtin_amdgcn_mfma_f32_16x16x32_f16(xa1, wcF[nt][1], a, 0,0,0);
          }
        }
        #pragma unroll
        for (int js=0; js<2; js++) {
          const int t = bs + s0 + js;
          if (js==1 && g==0 && b+1 < NBLK) XWRITE(buf^1);
          // recurrent h-chain; C-init = xp (bias+xproj pre-folded, D!=C copy-free)
          floatx4 ah[4];
          {
            const half_t* hrow = HR + ((t+15)&15)*HSLOT + (l16>>1)*HP;
            half8 ha[4];
            #pragma unroll
            for (int kc=0; kc<4; kc++) ha[kc] = *(const half8*)(hrow + kc*32 + quad*8);
            #pragma unroll
            for (int nt=0; nt<4; nt++) {
              floatx4 a = __builtin_amdgcn_mfma_f32_16x16x32_f16(ha[0], whhF[nt][0], xp[nt], 0,0,0);
              a = __builtin_amdgcn_mfma_f32_16x16x32_f16(ha[1], whhF[nt][1], a, 0,0,0);
              a = __builtin_amdgcn_mfma_f32_16x16x32_f16(ha[2], whhF[nt][2], a, 0,0,0);
              ah[nt] = __builtin_amdgcn_mfma_f32_16x16x32_f16(ha[3], whhF[nt][3], a, 0,0,0);
            }
          }
          #pragma unroll
          for (int bb=0; bb<2; bb++) {
            const int r = bb*2 + js;           // static after unroll
            float& cst = bb ? cst1 : cst0;
            cst = fsig(ah[1][r])*cst + fsig(ah[0][r])*ftanh(ah[2][r]);
            HR[(t&15)*HSLOT + (quad*2+bb)*HP + colw] = (half_t)(fsig(ah[3][r])*ftanh(cst));
          }
          __syncthreads();
        }
      }
      // bulk store this block's h to hs0, then publish (release)
      {
        const int hS = tid>>5, hR = (tid>>2)&7, hC = (tid&3)*32;
        if (hS < cnt) {
          half_t* dst = hs0 + ((size_t)(bs+hS)*NMB + nm0 + hR)*128 + hC;
          const half_t* src = HR + ((bs+hS)&15)*HSLOT + hR*HP + hC;
          #pragma unroll
          for (int k=0;k<4;k++) *(half8*)(dst + k*8) = *(const half8*)(src + k*8);
        }
      }
      __syncthreads();
      if (tid == 0)
        __hip_atomic_store(flag, b+1, __ATOMIC_RELEASE, __HIP_MEMORY_SCOPE_AGENT);
    }
  } else {
    // ================= layer-1 consumer (8 rows) + FC/softmax ====================
    half_t* XS = S;                   // [2][16][XROW1] = 39168 halfs
    half_t* H2 = S + 2*BS*XROW1;      // [2][HSLOT]     =  2432 halfs
    float* logits_lds = (float*)(smem + (2*BS*XROW1 + 2*HSLOT)*2);  // 480 f32
    const int wg  = blockIdx.x - 128;
    const int nm0 = wg*8;
    const int* flag = flags + wg*16;

    for (int i=tid; i<2*HSLOT; i+=512) H2[i] = (half_t)0.f;

    half8 whF[4][4], wxF[4][4]; floatx4 biasv[4];
    #pragma unroll
    for (int nt=0; nt<4; nt++) {
      const int gcol = nt*128 + colw;
      #pragma unroll
      for (int kc=0; kc<4; kc++) {
        wxF[nt][kc] = load_w8(wih1 + gcol*128 + kc*32 + quad*8); pin(wxF[nt][kc]);
        whF[nt][kc] = load_w8(whh1 + gcol*128 + kc*32 + quad*8); pin(whF[nt][kc]);
      }
      const float b = bih1[gcol] + bhh1[gcol];
      biasv[nt] = (floatx4){b,b,b,b}; pinf(biasv[nt]);
    }
    float cst0 = 0.f, cst1 = 0.f;

    // stage mapping: thread -> (step, row, 32-col strip); 4 x float4 per thread
    const int sS = tid>>5, sR = (tid>>2)&7, sC = (tid&3)*32;
    const int coff = sS*XROW1 + sR*HP + sC;
    float4 ld[4];
    wait_flag(flag, 1, tid);
    { const half_t* src = hs0 + ((size_t)sS*NMB + nm0 + sR)*128 + sC;
      #pragma unroll
      for (int k=0;k<4;k++) ld[k] = *(const float4*)(src + k*8); }
    #pragma unroll
    for (int k=0;k<4;k++) *(half8*)(XS + coff + k*8) = __builtin_bit_cast(half8, ld[k]);
    __syncthreads();

    for (int b=0; b<NBLK; b++) {
      const int bs = b*BS, buf = b&1;
      const int cnt = (T_STEPS - bs < BS) ? (T_STEPS - bs) : BS;
      const int ngr = cnt>>1;
      if (b+1 < NBLK) {
        wait_flag(flag, b+2, tid);
        int tt = bs + BS + sS; if (tt > 299) tt = 299;
        const half_t* src = hs0 + ((size_t)tt*NMB + nm0 + sR)*128 + sC;
        #pragma unroll
        for (int k=0;k<4;k++) ld[k] = *(const float4*)(src + k*8);
      }
      for (int g=0; g<ngr; g++) {
        const int s0 = g*2;
        // ---- batched xproj (batch-major rows), C-init = biasv
        floatx4 xp[4];
        {
          const half_t* xrow = XS + (buf*BS + s0 + (l16&1))*XROW1 + (l16>>1)*HP;
          half8 xa[4];
          #pragma unroll
          for (int kc=0; kc<4; kc++) xa[kc] = *(const half8*)(xrow + kc*32 + quad*8);
          #pragma unroll
          for (int nt=0; nt<4; nt++) {
            floatx4 a = __builtin_amdgcn_mfma_f32_16x16x32_f16(xa[0], wxF[nt][0], biasv[nt], 0,0,0);
            a = __builtin_amdgcn_mfma_f32_16x16x32_f16(xa[1], wxF[nt][1], a, 0,0,0);
            a = __builtin_amdgcn_mfma_f32_16x16x32_f16(xa[2], wxF[nt][2], a, 0,0,0);
            xp[nt] = __builtin_amdgcn_mfma_f32_16x16x32_f16(xa[3], wxF[nt][3], a, 0,0,0);
          }
        }
        #pragma unroll
        for (int js=0; js<2; js++) {
          const int t = bs + s0 + js;
          if (js==1 && g==0 && b+1 < NBLK) {
            #pragma unroll
            for (int k=0;k<4;k++) *(half8*)(XS + ((buf^1)*BS)*XROW1 + coff + k*8) = __builtin_bit_cast(half8, ld[k]);
          }
          // recurrent h-chain; C-init = xp (copy-free D!=C)
          floatx4 ah[4];
          {
            const half_t* hrow = H2 + (t&1)*HSLOT + (l16>>1)*HP;
            half8 ha[4];
            #pragma unroll
            for (int kc=0; kc<4; kc++) ha[kc] = *(const half8*)(hrow + kc*32 + quad*8);
            #pragma unroll
            for (int nt=0; nt<4; nt++) {
              floatx4 a = __builtin_amdgcn_mfma_f32_16x16x32_f16(ha[0], whF[nt][0], xp[nt], 0,0,0);
              a = __builtin_amdgcn_mfma_f32_16x16x32_f16(ha[1], whF[nt][1], a, 0,0,0);
              a = __builtin_amdgcn_mfma_f32_16x16x32_f16(ha[2], whF[nt][2], a, 0,0,0);
              ah[nt] = __builtin_amdgcn_mfma_f32_16x16x32_f16(ha[3], whF[nt][3], a, 0,0,0);
            }
          }
          #pragma unroll
          for (int bb=0; bb<2; bb++) {
            const int r = bb*2 + js;
            float& cst = bb ? cst1 : cst0;
            cst = fsig(ah[1][r])*cst + fsig(ah[0][r])*ftanh(ah[2][r]);
            H2[((t+1)&1)*HSLOT + (quad*2+bb)*HP + colw] = (half_t)(fsig(ah[3][r])*ftanh(cst));
          }
          __syncthreads();
        }
      }
    }

    // ---- FC (60 classes) + softmax; h1[299] in H2 buffer 0, rows 0..7
    if (tid < 480) {
      const int rr = tid/60, cls = tid%60;
      float s = fcb[cls];
      for (int k2=0; k2<128; k2++) s += (float)H2[rr*HP + k2] * fcw[cls*128+k2];
      logits_lds[rr*60+cls] = s;
    }
    __syncthreads();
    if (tid < 8) {
      float m = -1e30f;
      for (int j=0; j<60; j++) m = fmaxf(m, logits_lds[tid*60+j]);
      float s = 0.f;
      for (int j=0; j<60; j++) s += __expf(logits_lds[tid*60+j]-m);
      const float inv = frcp(s);
      for (int j=0; j<60; j++) out[(nm0+tid)*60+j] = __expf(logits_lds[tid*60+j]-m)*inv;
    }
  }
}

extern "C" void kernel_launch(void* const* d_in, const int* in_sizes, int n_in,
                              void* d_out, int out_size, void* d_ws, size_t ws_size,
                              hipStream_t stream) {
  const float* x1      = (const float*)d_in[0];
  const float* cheb_w0 = (const float*)d_in[2];
  const float* cheb_w1 = (const float*)d_in[3];
  const float* cheb_b  = (const float*)d_in[4];
  const float* wih0    = (const float*)d_in[5];
  const float* whh0    = (const float*)d_in[6];
  const float* bih0    = (const float*)d_in[7];
  const float* bhh0    = (const float*)d_in[8];
  const float* wih1    = (const float*)d_in[9];
  const float* whh1    = (const float*)d_in[10];
  const float* bih1    = (const float*)d_in[11];
  const float* bhh1    = (const float*)d_in[12];
  const float* fc_w    = (const float*)d_in[13];
  const float* fc_b    = (const float*)d_in[14];

  char* ws = (char*)d_ws;
  half_t* hs0   = (half_t*)(ws + HS0_OFF);
  half_t* wch   = (half_t*)(ws + WCH_OFF);
  float*  biasc = (float*)(ws + BC_OFF);
  int*    flags = (int*)(ws + FLAG_OFF);

  k_prep<<<dim3(1), dim3(512), 0, stream>>>(cheb_w0, cheb_w1, cheb_b, wih0, bih0, bhh0, wch, biasc, flags);
  k_lstm_fused<<<dim3(256), dim3(512), 0, stream>>>(
      x1, wch, biasc, whh0, hs0, wih1, whh1, bih1, bhh1, fc_w, fc_b, (float*)d_out, flags);
}